// Round 3
// baseline (742.480 us; speedup 1.0000x reference)
//
#include <hip/hip_runtime.h>
#include <cstdint>

#define BN_EPS 1e-5f

// ---------- CSR build ----------

__global__ __launch_bounds__(256) void k_count(const int* __restrict__ dstv,
                                               int* __restrict__ counts, int E) {
  int e = blockIdx.x * 256 + threadIdx.x;
  if (e < E) atomicAdd(counts + dstv[e], 1);
}

__global__ __launch_bounds__(256) void k_dis(const int* __restrict__ counts,
                                             float* __restrict__ dis, int N) {
  int i = blockIdx.x * 256 + threadIdx.x;
  if (i < N) dis[i] = rsqrtf((float)counts[i] + 1.0f);
}

// per-block (1024 elems) exclusive scan; block total -> bsum
__global__ __launch_bounds__(256) void k_scan1(const int* __restrict__ counts,
                                               int* __restrict__ rowstart,
                                               int* __restrict__ bsum, int N) {
  __shared__ int wsum[4];
  const int tid = threadIdx.x, lane = tid & 63, wv = tid >> 6;
  const int base = blockIdx.x * 1024 + tid * 4;
  int c[4];
#pragma unroll
  for (int j = 0; j < 4; ++j) {
    int idx = base + j;
    c[j] = (idx < N) ? counts[idx] : 0;
  }
  int s = c[0] + c[1] + c[2] + c[3];
  int x = s;  // inclusive wave scan
  for (int d = 1; d < 64; d <<= 1) {
    int y = __shfl_up(x, d);
    if (lane >= d) x += y;
  }
  if (lane == 63) wsum[wv] = x;
  __syncthreads();
  int woff = 0;
  for (int w = 0; w < wv; ++w) woff += wsum[w];
  int r = woff + x - s;
#pragma unroll
  for (int j = 0; j < 4; ++j) {
    int idx = base + j;
    if (idx < N) rowstart[idx] = r;
    r += c[j];
  }
  if (tid == 255) bsum[blockIdx.x] = woff + x;
}

__global__ __launch_bounds__(256) void k_scan2(const int* __restrict__ bsum,
                                               int* __restrict__ boff, int nb) {
  __shared__ int sm[256];
  const int tid = threadIdx.x;
  int v = (tid < nb) ? bsum[tid] : 0;
  sm[tid] = v;
  __syncthreads();
  for (int d = 1; d < 256; d <<= 1) {
    int y = (tid >= d) ? sm[tid - d] : 0;
    __syncthreads();
    sm[tid] += y;
    __syncthreads();
  }
  if (tid < nb) boff[tid] = sm[tid] - v;
}

__global__ __launch_bounds__(256) void k_fix(int* __restrict__ rowstart,
                                             const int* __restrict__ boff,
                                             int* __restrict__ cursor, int N) {
  int i = blockIdx.x * 256 + threadIdx.x;
  if (i < N) {
    int v = rowstart[i] + boff[i >> 10];
    rowstart[i] = v;
    cursor[i] = v;
  }
}

__global__ __launch_bounds__(256) void k_scatter(const int* __restrict__ src,
                                                 const int* __restrict__ dstv,
                                                 const float* __restrict__ dis,
                                                 int* __restrict__ cursor,
                                                 int* __restrict__ esrc,
                                                 float* __restrict__ ecoef, int E) {
  int e = blockIdx.x * 256 + threadIdx.x;
  if (e < E) {
    int s = src[e], d = dstv[e];
    int p = atomicAdd(cursor + d, 1);
    esrc[p] = s;
    ecoef[p] = dis[s] * dis[d];
  }
}

__global__ __launch_bounds__(256) void k_bnparam(const float* __restrict__ gamma,
                                                 const float* __restrict__ beta,
                                                 const float* __restrict__ mean,
                                                 const float* __restrict__ var,
                                                 float* __restrict__ scale,
                                                 float* __restrict__ shift, int n) {
  int i = blockIdx.x * 256 + threadIdx.x;
  if (i < n) {
    float s = gamma[i] * rsqrtf(var[i] + BN_EPS);
    scale[i] = s;
    shift[i] = beta[i] - mean[i] * s;
  }
}

// ---------- fused layer: [gather agg + bias + BN + ReLU] -> GEMM ----------
// BM=64 rows per block, 256 threads (4 waves).
// Phase 1: each wave builds rows r = wv, wv+4, ... of the h-tile in LDS:
//   GATHER: h = relu(bn(sum_e coef*t[src] + t[node]/deg + bias))
//   else:   h = t_in row (first layer: x)
// Phase 2: 16x16 thread grid, per-thread 4 x TN register tile, A from LDS
//   (row-swizzled, conflict-free), W staged per KSTEP chunk (XOR-swizzled).
// LDS = 64*128*4 + 16*BNC*4 = 40960 B (BNC=128) -> 4 blocks/CU.
template <int BNC, int TN, bool GATHER, bool APPLY_BN, bool FINAL>
__global__ __launch_bounds__(256, 4) void k_fused(
    const float* __restrict__ t_in, const float* __restrict__ W,
    const float* __restrict__ bias, const float* __restrict__ scale,
    const float* __restrict__ shift, const float* __restrict__ out_bias,
    const int* __restrict__ rowstart, const int* __restrict__ counts,
    const int* __restrict__ esrc, const float* __restrict__ ecoef,
    const float* __restrict__ dis, float* __restrict__ out_p, int N) {
  constexpr int BM = 64;
  constexpr int KSTEP = 16;
  __shared__ float h_rm[BM * 128];   // row-major, 4-float groups XOR-swizzled by (row&7)
  __shared__ float Wl[KSTEP * BNC];  // XOR-swizzled groups

  const int tid = threadIdx.x;
  const int lane = tid & 63;
  const int wv = tid >> 6;
  const int rowBase = blockIdx.x * BM;

  // ---- phase 1: build h tile ----
  {
    const int f0 = lane * 2;
    float scx = 0.f, scy = 0.f, shx = 0.f, shy = 0.f, bx = 0.f, by = 0.f;
    if constexpr (APPLY_BN) {
      scx = scale[f0]; scy = scale[f0 + 1];
      shx = shift[f0]; shy = shift[f0 + 1];
    }
    if constexpr (GATHER) { bx = bias[f0]; by = bias[f0 + 1]; }
    for (int r = wv; r < BM; r += 4) {
      const int node = rowBase + r;
      float ax = 0.f, ay = 0.f;
      if (node < N) {
        if constexpr (GATHER) {
          const float dn = dis[node];
          const float dsq = dn * dn;
          const float2 sv = *reinterpret_cast<const float2*>(t_in + (size_t)node * 128 + f0);
          ax = sv.x * dsq;
          ay = sv.y * dsq;
          const int beg = rowstart[node];
          const int cnt = counts[node];
          int i = 0;
          for (; i + 4 <= cnt; i += 4) {
            const int s0 = esrc[beg + i + 0], s1 = esrc[beg + i + 1];
            const int s2 = esrc[beg + i + 2], s3 = esrc[beg + i + 3];
            const float c0 = ecoef[beg + i + 0], c1 = ecoef[beg + i + 1];
            const float c2 = ecoef[beg + i + 2], c3 = ecoef[beg + i + 3];
            const float2 v0 = *reinterpret_cast<const float2*>(t_in + (size_t)s0 * 128 + f0);
            const float2 v1 = *reinterpret_cast<const float2*>(t_in + (size_t)s1 * 128 + f0);
            const float2 v2 = *reinterpret_cast<const float2*>(t_in + (size_t)s2 * 128 + f0);
            const float2 v3 = *reinterpret_cast<const float2*>(t_in + (size_t)s3 * 128 + f0);
            ax = fmaf(v0.x, c0, ax); ay = fmaf(v0.y, c0, ay);
            ax = fmaf(v1.x, c1, ax); ay = fmaf(v1.y, c1, ay);
            ax = fmaf(v2.x, c2, ax); ay = fmaf(v2.y, c2, ay);
            ax = fmaf(v3.x, c3, ax); ay = fmaf(v3.y, c3, ay);
          }
          for (; i < cnt; ++i) {
            const int s0 = esrc[beg + i];
            const float c0 = ecoef[beg + i];
            const float2 v0 = *reinterpret_cast<const float2*>(t_in + (size_t)s0 * 128 + f0);
            ax = fmaf(v0.x, c0, ax); ay = fmaf(v0.y, c0, ay);
          }
          ax += bx; ay += by;
        } else {
          const float2 sv = *reinterpret_cast<const float2*>(t_in + (size_t)node * 128 + f0);
          ax = sv.x; ay = sv.y;
        }
        if constexpr (APPLY_BN) {
          ax = fmaxf(fmaf(ax, scx, shx), 0.f);
          ay = fmaxf(fmaf(ay, scy, shy), 0.f);
        }
      }
      const int gg = (((f0 >> 2) ^ (r & 7)) << 2) + (f0 & 3);
      h_rm[r * 128 + gg] = ax;
      h_rm[r * 128 + gg + 1] = ay;
    }
  }
  __syncthreads();

  // ---- phase 2: GEMM ----
  const int tx = tid & 15, ty = tid >> 4;
  const int r0 = ty * 4;
  const int j0 = tx * TN;
  float acc[4][TN];
#pragma unroll
  for (int m = 0; m < 4; ++m)
#pragma unroll
    for (int n = 0; n < TN; ++n) acc[m][n] = 0.f;

  for (int kc = 0; kc < 128; kc += KSTEP) {
#pragma unroll
    for (int p = 0; p < (KSTEP * BNC) / 1024; ++p) {
      const int idx = (tid + p * 256) * 4;
      const int k = idx / BNC, j = idx % BNC;
      const int g = j >> 2;
      const int gs = g ^ (g >> 3);
      const float4 v = *reinterpret_cast<const float4*>(W + (size_t)(kc + k) * BNC + j);
      *reinterpret_cast<float4*>(&Wl[k * BNC + (gs << 2)]) = v;
    }
    __syncthreads();
#pragma unroll
    for (int kk = 0; kk < KSTEP / 4; ++kk) {
      float avf[4][4];
#pragma unroll
      for (int m = 0; m < 4; ++m) {
        const int r = r0 + m;
        const int gg = (((kc >> 2) + kk) ^ (r & 7)) << 2;
        const float4 v = *reinterpret_cast<const float4*>(&h_rm[r * 128 + gg]);
        avf[m][0] = v.x; avf[m][1] = v.y; avf[m][2] = v.z; avf[m][3] = v.w;
      }
#pragma unroll
      for (int q = 0; q < 4; ++q) {
        const int k = kk * 4 + q;
        float b[TN];
#pragma unroll
        for (int n4 = 0; n4 < TN / 4; ++n4) {
          const int g = (j0 >> 2) + n4;
          const int gs = g ^ (g >> 3);
          *reinterpret_cast<float4*>(&b[n4 * 4]) =
              *reinterpret_cast<const float4*>(&Wl[k * BNC + (gs << 2)]);
        }
#pragma unroll
        for (int m = 0; m < 4; ++m)
#pragma unroll
          for (int n = 0; n < TN; ++n) acc[m][n] = fmaf(avf[m][q], b[n], acc[m][n]);
      }
    }
    __syncthreads();
  }

  // ---- epilogue ----
  float ob[TN];
  if constexpr (FINAL) {
#pragma unroll
    for (int n = 0; n < TN; ++n) ob[n] = out_bias[j0 + n];
  }
#pragma unroll
  for (int m = 0; m < 4; ++m) {
    const int row = rowBase + r0 + m;
    if (row < N) {
      if constexpr (FINAL) {
        float o[TN];
#pragma unroll
        for (int n = 0; n < TN; ++n) o[n] = acc[m][n] + ob[n];
#pragma unroll
        for (int n4 = 0; n4 < TN / 4; ++n4)
          *reinterpret_cast<float4*>(out_p + (size_t)row * BNC + j0 + n4 * 4) =
              *reinterpret_cast<const float4*>(&o[n4 * 4]);
      } else {
#pragma unroll
        for (int n4 = 0; n4 < TN / 4; ++n4)
          *reinterpret_cast<float4*>(out_p + (size_t)row * BNC + j0 + n4 * 4) =
              *reinterpret_cast<const float4*>(&acc[m][n4 * 4]);
      }
    }
  }
}

// ---------- launch ----------
extern "C" void kernel_launch(void* const* d_in, const int* in_sizes, int n_in,
                              void* d_out, int out_size, void* d_ws, size_t ws_size,
                              hipStream_t stream) {
  const float* x      = (const float*)d_in[0];
  const int*   ei     = (const int*)d_in[1];
  const float* W_in   = (const float*)d_in[2];
  const float* b_in   = (const float*)d_in[3];
  const float* Ws     = (const float*)d_in[4];
  const float* bs     = (const float*)d_in[5];
  const float* gammas = (const float*)d_in[6];
  const float* betas  = (const float*)d_in[7];
  const float* mean   = (const float*)d_in[8];
  const float* var    = (const float*)d_in[9];
  const float* W_out  = (const float*)d_in[10];
  const float* b_out  = (const float*)d_in[11];
  float* out = (float*)d_out;

  const int N = in_sizes[0] / 128;
  const int E = in_sizes[1] / 2;
  const int* src = ei;
  const int* dst = ei + E;

  char* ws = (char*)d_ws;
  size_t off = 0;
  auto alloc = [&](size_t bytes) {
    void* p = ws + off;
    off = (off + bytes + 255) & ~255ULL;
    return p;
  };
  int*   counts   = (int*)alloc((size_t)N * 4);
  int*   rowstart = (int*)alloc((size_t)N * 4);
  int*   cursor   = (int*)alloc((size_t)N * 4);
  int*   bsum     = (int*)alloc(256 * 4);
  int*   boff     = (int*)alloc(256 * 4);
  float* dis      = (float*)alloc((size_t)N * 4);
  float* scale    = (float*)alloc(5 * 128 * 4);
  float* shift    = (float*)alloc(5 * 128 * 4);
  int*   esrc     = (int*)alloc((size_t)E * 4);
  float* ecoef    = (float*)alloc((size_t)E * 4);
  float* tA       = (float*)alloc((size_t)N * 128 * 4);
  float* tB       = (float*)alloc((size_t)N * 128 * 4);
  (void)ws_size;

  const int nb = (N + 1023) / 1024;

  hipMemsetAsync(counts, 0, (size_t)N * 4, stream);
  k_count<<<(E + 255) / 256, 256, 0, stream>>>(dst, counts, E);
  k_dis<<<(N + 255) / 256, 256, 0, stream>>>(counts, dis, N);
  k_scan1<<<nb, 256, 0, stream>>>(counts, rowstart, bsum, N);
  k_scan2<<<1, 256, 0, stream>>>(bsum, boff, nb);
  k_fix<<<(N + 255) / 256, 256, 0, stream>>>(rowstart, boff, cursor, N);
  k_scatter<<<(E + 255) / 256, 256, 0, stream>>>(src, dst, dis, cursor, esrc, ecoef, E);
  k_bnparam<<<(5 * 128 + 255) / 256, 256, 0, stream>>>(gammas, betas, mean, var,
                                                       scale, shift, 5 * 128);

  const int fblocks = (N + 63) / 64;

  // G0: t = x @ W_in   (bias folded into next layer's aggregation)
  k_fused<128, 8, false, false, false><<<fblocks, 256, 0, stream>>>(
      x, W_in, nullptr, nullptr, nullptr, nullptr,
      nullptr, nullptr, nullptr, nullptr, nullptr, tA, N);

  // F1..F4: t_{l} = relu(bn_{l-1}(agg(t_{l-1}) + b_{l-1})) @ W_l
  const float* tin = tA;
  float* tout = tB;
  for (int l = 1; l <= 4; ++l) {
    const float* b = (l == 1) ? b_in : bs + (size_t)(l - 2) * 128;
    const float* Wl_ = Ws + (size_t)(l - 1) * 128 * 128;
    k_fused<128, 8, true, true, false><<<fblocks, 256, 0, stream>>>(
        tin, Wl_, b, scale + (size_t)(l - 1) * 128, shift + (size_t)(l - 1) * 128,
        nullptr, rowstart, counts, esrc, ecoef, dis, tout, N);
    const float* tmp = tin;
    tin = tout;
    tout = (float*)tmp;
  }

  // F5: out = relu(bn_4(agg(t_4) + b_4)) @ W_out + b_out
  k_fused<64, 4, true, true, true><<<fblocks, 256, 0, stream>>>(
      tin, W_out, bs + 3 * 128, scale + 4 * 128, shift + 4 * 128, b_out,
      rowstart, counts, esrc, ecoef, dis, out, N);
}

// Round 4
// 582.734 us; speedup vs baseline: 1.2741x; 1.2741x over previous
//
#include <hip/hip_runtime.h>
#include <cstdint>

#define BN_EPS 1e-5f

typedef __bf16 bf16x8 __attribute__((ext_vector_type(8)));
typedef __bf16 bf16x4 __attribute__((ext_vector_type(4)));
typedef float f32x4 __attribute__((ext_vector_type(4)));

// ---------- CSR build ----------

__global__ __launch_bounds__(256) void k_count(const int* __restrict__ dstv,
                                               int* __restrict__ counts, int E) {
  int e = blockIdx.x * 256 + threadIdx.x;
  if (e < E) atomicAdd(counts + dstv[e], 1);
}

__global__ __launch_bounds__(256) void k_dis(const int* __restrict__ counts,
                                             float* __restrict__ dis, int N) {
  int i = blockIdx.x * 256 + threadIdx.x;
  if (i < N) dis[i] = rsqrtf((float)counts[i] + 1.0f);
}

// per-block (1024 elems) exclusive scan; block total -> bsum
__global__ __launch_bounds__(256) void k_scan1(const int* __restrict__ counts,
                                               int* __restrict__ rowstart,
                                               int* __restrict__ bsum, int N) {
  __shared__ int wsum[4];
  const int tid = threadIdx.x, lane = tid & 63, wv = tid >> 6;
  const int base = blockIdx.x * 1024 + tid * 4;
  int c[4];
#pragma unroll
  for (int j = 0; j < 4; ++j) {
    int idx = base + j;
    c[j] = (idx < N) ? counts[idx] : 0;
  }
  int s = c[0] + c[1] + c[2] + c[3];
  int x = s;  // inclusive wave scan
  for (int d = 1; d < 64; d <<= 1) {
    int y = __shfl_up(x, d);
    if (lane >= d) x += y;
  }
  if (lane == 63) wsum[wv] = x;
  __syncthreads();
  int woff = 0;
  for (int w = 0; w < wv; ++w) woff += wsum[w];
  int r = woff + x - s;
#pragma unroll
  for (int j = 0; j < 4; ++j) {
    int idx = base + j;
    if (idx < N) rowstart[idx] = r;
    r += c[j];
  }
  if (tid == 255) bsum[blockIdx.x] = woff + x;
}

__global__ __launch_bounds__(256) void k_scan2(const int* __restrict__ bsum,
                                               int* __restrict__ boff, int nb) {
  __shared__ int sm[256];
  const int tid = threadIdx.x;
  int v = (tid < nb) ? bsum[tid] : 0;
  sm[tid] = v;
  __syncthreads();
  for (int d = 1; d < 256; d <<= 1) {
    int y = (tid >= d) ? sm[tid - d] : 0;
    __syncthreads();
    sm[tid] += y;
    __syncthreads();
  }
  if (tid < nb) boff[tid] = sm[tid] - v;
}

__global__ __launch_bounds__(256) void k_fix(int* __restrict__ rowstart,
                                             const int* __restrict__ boff,
                                             int* __restrict__ cursor, int N) {
  int i = blockIdx.x * 256 + threadIdx.x;
  if (i < N) {
    int v = rowstart[i] + boff[i >> 10];
    rowstart[i] = v;
    cursor[i] = v;
  }
}

__global__ __launch_bounds__(256) void k_scatter(const int* __restrict__ src,
                                                 const int* __restrict__ dstv,
                                                 const float* __restrict__ dis,
                                                 int* __restrict__ cursor,
                                                 int* __restrict__ esrc,
                                                 float* __restrict__ ecoef, int E) {
  int e = blockIdx.x * 256 + threadIdx.x;
  if (e < E) {
    int s = src[e], d = dstv[e];
    int p = atomicAdd(cursor + d, 1);
    esrc[p] = s;
    ecoef[p] = dis[s] * dis[d];
  }
}

__global__ __launch_bounds__(256) void k_bnparam(const float* __restrict__ gamma,
                                                 const float* __restrict__ beta,
                                                 const float* __restrict__ mean,
                                                 const float* __restrict__ var,
                                                 float* __restrict__ scale,
                                                 float* __restrict__ shift, int n) {
  int i = blockIdx.x * 256 + threadIdx.x;
  if (i < n) {
    float s = gamma[i] * rsqrtf(var[i] + BN_EPS);
    scale[i] = s;
    shift[i] = beta[i] - mean[i] * s;
  }
}

// ---------- weight prep: transpose to [n][k] and split fp32 -> bf16 hi + lo ----------
// layout in wt_hi/wt_lo: layers 0..4 at l*16384 (128x128), final at 81920 (64x128)
__global__ __launch_bounds__(256) void k_wprep(const float* __restrict__ W_in,
                                               const float* __restrict__ Ws,
                                               const float* __restrict__ W_out,
                                               __bf16* __restrict__ wt_hi,
                                               __bf16* __restrict__ wt_lo) {
  int idx = blockIdx.x * 256 + threadIdx.x;
  float v;
  int dst;
  if (idx < 81920) {
    int l = idx >> 14, r = idx & 16383, k = r >> 7, n = r & 127;
    v = (l == 0) ? W_in[k * 128 + n] : Ws[(size_t)(l - 1) * 16384 + k * 128 + n];
    dst = l * 16384 + n * 128 + k;
  } else if (idx < 90112) {
    int r = idx - 81920, k = r >> 6, n = r & 63;
    v = W_out[k * 64 + n];
    dst = 81920 + n * 128 + k;
  } else {
    return;
  }
  __bf16 hi = (__bf16)v;
  float lof = v - (float)hi;
  wt_hi[dst] = hi;
  wt_lo[dst] = (__bf16)lof;
}

// ---------- MFMA GEMM (bf16 hi/lo split ~= fp32): out[N,BNC] = act(in)[N,128] @ W ----------
// BM=128 rows/block, 256 threads = 4 waves; wave wv owns rows wv*32..wv*32+31 (2 rowtiles),
// all BNC columns (CT coltiles). A staged fp32->bf16 hi/lo in LDS (XOR swizzle), W chunk
// (32 k) staged per iter from precomputed transposed hi/lo bf16 weights.
// LDS = 64KB (A) + BNC*128 B (W chunk) -> 80KB at BNC=128 -> 2 blocks/CU.
template <int BNC, bool APPLY_BN, bool FINAL>
__global__ __launch_bounds__(256, 2) void k_mgemm(
    const float* __restrict__ in, const __bf16* __restrict__ wt_hi,
    const __bf16* __restrict__ wt_lo, const float* __restrict__ scale,
    const float* __restrict__ shift, const float* __restrict__ out_bias,
    float* __restrict__ out_p, int N) {
  constexpr int CT = BNC / 16;
  __shared__ __align__(16) char smem[65536 + BNC * 128];
  char* const Abase = smem;          // [2 planes][128 rows][128 k] bf16, swizzled
  char* const Bbase = smem + 65536;  // [2 planes][BNC cols][32 k] bf16, swizzled

  const int tid = threadIdx.x;
  const int lane = tid & 63;
  const int wv = tid >> 6;
  const int lr = lane & 15;
  const int kg = lane >> 4;
  const int rowBase = blockIdx.x * 128;

  // ---- stage A: fp32 -> (bn+relu) -> bf16 hi/lo planes ----
  {
    const int kq = tid & 31;  // which float4 of the row (constant per thread)
    float4 sc4 = make_float4(0.f, 0.f, 0.f, 0.f), sh4 = sc4;
    if constexpr (APPLY_BN) {
      sc4 = *(const float4*)(scale + kq * 4);
      sh4 = *(const float4*)(shift + kq * 4);
    }
#pragma unroll
    for (int i = 0; i < 16; ++i) {
      const int row = (tid >> 5) + i * 8;
      const int grow = rowBase + row;
      float4 v = make_float4(0.f, 0.f, 0.f, 0.f);
      if (grow < N) v = *(const float4*)(in + (size_t)grow * 128 + kq * 4);
      if constexpr (APPLY_BN) {
        v.x = fmaxf(fmaf(v.x, sc4.x, sh4.x), 0.f);
        v.y = fmaxf(fmaf(v.y, sc4.y, sh4.y), 0.f);
        v.z = fmaxf(fmaf(v.z, sc4.z, sh4.z), 0.f);
        v.w = fmaxf(fmaf(v.w, sc4.w, sh4.w), 0.f);
      }
      bf16x4 hi, lo;
      hi[0] = (__bf16)v.x; lo[0] = (__bf16)(v.x - (float)hi[0]);
      hi[1] = (__bf16)v.y; lo[1] = (__bf16)(v.y - (float)hi[1]);
      hi[2] = (__bf16)v.z; lo[2] = (__bf16)(v.z - (float)hi[2]);
      hi[3] = (__bf16)v.w; lo[3] = (__bf16)(v.w - (float)hi[3]);
      int byte = row * 256 + kq * 8;
      byte ^= (row & 7) << 4;
      *(bf16x4*)(Abase + byte) = hi;
      *(bf16x4*)(Abase + 32768 + byte) = lo;
    }
  }

  f32x4 acc[2][CT] = {};

  for (int kc = 0; kc < 128; kc += 32) {
    __syncthreads();  // first iter: A staged; later: waves done reading prev W chunk
    // ---- stage W chunk (both planes) ----
#pragma unroll
    for (int hl = 0; hl < 2; ++hl) {
      const __bf16* wsrc = hl ? wt_lo : wt_hi;
#pragma unroll
      for (int p = 0; p < BNC / 64; ++p) {
        const int u = tid + p * 256;
        const int n = u >> 2, kslot = u & 3;
        uint4 v = *(const uint4*)(wsrc + (size_t)n * 128 + kc + kslot * 8);
        int byte = n * 64 + kslot * 16;
        byte ^= (n & 7) << 4;
        *(uint4*)(Bbase + hl * (BNC * 64) + byte) = v;
      }
    }
    __syncthreads();
    // ---- compute ----
    bf16x8 afr[2][2];  // [rowtile][hi/lo]
#pragma unroll
    for (int rt = 0; rt < 2; ++rt) {
      const int row = wv * 32 + rt * 16 + lr;
      int byte = row * 256 + kc * 2 + kg * 16;
      byte ^= (row & 7) << 4;
      afr[rt][0] = *(const bf16x8*)(Abase + byte);
      afr[rt][1] = *(const bf16x8*)(Abase + 32768 + byte);
    }
#pragma unroll
    for (int ct = 0; ct < CT; ++ct) {
      const int col = ct * 16 + lr;
      int byte = col * 64 + kg * 16;
      byte ^= (col & 7) << 4;
      bf16x8 bhi = *(const bf16x8*)(Bbase + byte);
      bf16x8 blo = *(const bf16x8*)(Bbase + BNC * 64 + byte);
#pragma unroll
      for (int rt = 0; rt < 2; ++rt) {
        acc[rt][ct] = __builtin_amdgcn_mfma_f32_16x16x32_bf16(afr[rt][0], bhi,
                                                              acc[rt][ct], 0, 0, 0);
        acc[rt][ct] = __builtin_amdgcn_mfma_f32_16x16x32_bf16(afr[rt][0], blo,
                                                              acc[rt][ct], 0, 0, 0);
        acc[rt][ct] = __builtin_amdgcn_mfma_f32_16x16x32_bf16(afr[rt][1], bhi,
                                                              acc[rt][ct], 0, 0, 0);
      }
    }
  }

  // ---- epilogue: C/D layout col=lane&15, row=(lane>>4)*4+j ----
  float ob[CT];
  if constexpr (FINAL) {
#pragma unroll
    for (int ct = 0; ct < CT; ++ct) ob[ct] = out_bias[ct * 16 + lr];
  }
#pragma unroll
  for (int rt = 0; rt < 2; ++rt) {
#pragma unroll
    for (int j = 0; j < 4; ++j) {
      const int row = rowBase + wv * 32 + rt * 16 + kg * 4 + j;
      if (row < N) {
#pragma unroll
        for (int ct = 0; ct < CT; ++ct) {
          const int col = ct * 16 + lr;
          float o = acc[rt][ct][j];
          if constexpr (FINAL) o += ob[ct];
          out_p[(size_t)row * BNC + col] = o;
        }
      }
    }
  }
}

// ---------- CSR gather: agg[d] = sum_e t[src_e]*coef_e + t[d]/deg + bias ----------
__global__ __launch_bounds__(256) void k_agg(const int* __restrict__ rowstart,
                                             const int* __restrict__ counts,
                                             const int* __restrict__ esrc,
                                             const float* __restrict__ ecoef,
                                             const float* __restrict__ t,
                                             const float* __restrict__ dis,
                                             const float* __restrict__ bias,
                                             float* __restrict__ agg, int N) {
  const int lane = threadIdx.x & 63;
  const int wv = threadIdx.x >> 6;
  const int node = blockIdx.x * 4 + wv;
  if (node >= N) return;
  const int beg = rowstart[node];
  const int cnt = counts[node];
  const float dsq = dis[node] * dis[node];

  float2 acc = *reinterpret_cast<const float2*>(t + (size_t)node * 128 + lane * 2);
  acc.x *= dsq;
  acc.y *= dsq;

  int i = 0;
  for (; i + 2 <= cnt; i += 2) {
    const int s0 = esrc[beg + i], s1 = esrc[beg + i + 1];
    const float c0 = ecoef[beg + i], c1 = ecoef[beg + i + 1];
    float2 v0 = *reinterpret_cast<const float2*>(t + (size_t)s0 * 128 + lane * 2);
    float2 v1 = *reinterpret_cast<const float2*>(t + (size_t)s1 * 128 + lane * 2);
    acc.x = fmaf(v0.x, c0, acc.x);
    acc.y = fmaf(v0.y, c0, acc.y);
    acc.x = fmaf(v1.x, c1, acc.x);
    acc.y = fmaf(v1.y, c1, acc.y);
  }
  if (i < cnt) {
    const int s0 = esrc[beg + i];
    const float c0 = ecoef[beg + i];
    float2 v0 = *reinterpret_cast<const float2*>(t + (size_t)s0 * 128 + lane * 2);
    acc.x = fmaf(v0.x, c0, acc.x);
    acc.y = fmaf(v0.y, c0, acc.y);
  }
  acc.x += bias[lane * 2 + 0];
  acc.y += bias[lane * 2 + 1];
  *reinterpret_cast<float2*>(agg + (size_t)node * 128 + lane * 2) = acc;
}

// ---------- launch ----------
extern "C" void kernel_launch(void* const* d_in, const int* in_sizes, int n_in,
                              void* d_out, int out_size, void* d_ws, size_t ws_size,
                              hipStream_t stream) {
  const float* x      = (const float*)d_in[0];
  const int*   ei     = (const int*)d_in[1];
  const float* W_in   = (const float*)d_in[2];
  const float* b_in   = (const float*)d_in[3];
  const float* Ws     = (const float*)d_in[4];
  const float* bs     = (const float*)d_in[5];
  const float* gammas = (const float*)d_in[6];
  const float* betas  = (const float*)d_in[7];
  const float* mean   = (const float*)d_in[8];
  const float* var    = (const float*)d_in[9];
  const float* W_out  = (const float*)d_in[10];
  const float* b_out  = (const float*)d_in[11];
  float* out = (float*)d_out;

  const int N = in_sizes[0] / 128;
  const int E = in_sizes[1] / 2;
  const int* src = ei;
  const int* dst = ei + E;

  char* ws = (char*)d_ws;
  size_t off = 0;
  auto alloc = [&](size_t bytes) {
    void* p = ws + off;
    off = (off + bytes + 255) & ~255ULL;
    return p;
  };
  int*    counts   = (int*)alloc((size_t)N * 4);
  int*    rowstart = (int*)alloc((size_t)N * 4);
  int*    cursor   = (int*)alloc((size_t)N * 4);
  int*    bsum     = (int*)alloc(256 * 4);
  int*    boff     = (int*)alloc(256 * 4);
  float*  dis      = (float*)alloc((size_t)N * 4);
  float*  scale    = (float*)alloc(5 * 128 * 4);
  float*  shift    = (float*)alloc(5 * 128 * 4);
  __bf16* wt_hi    = (__bf16*)alloc(90112 * 2);
  __bf16* wt_lo    = (__bf16*)alloc(90112 * 2);
  int*    esrc     = (int*)alloc((size_t)E * 4);
  float*  ecoef    = (float*)alloc((size_t)E * 4);
  float*  t        = (float*)alloc((size_t)N * 128 * 4);
  float*  agg      = (float*)alloc((size_t)N * 128 * 4);
  (void)ws_size;

  const int nb = (N + 1023) / 1024;

  hipMemsetAsync(counts, 0, (size_t)N * 4, stream);
  k_count<<<(E + 255) / 256, 256, 0, stream>>>(dst, counts, E);
  k_dis<<<(N + 255) / 256, 256, 0, stream>>>(counts, dis, N);
  k_scan1<<<nb, 256, 0, stream>>>(counts, rowstart, bsum, N);
  k_scan2<<<1, 256, 0, stream>>>(bsum, boff, nb);
  k_fix<<<(N + 255) / 256, 256, 0, stream>>>(rowstart, boff, cursor, N);
  k_scatter<<<(E + 255) / 256, 256, 0, stream>>>(src, dst, dis, cursor, esrc, ecoef, E);
  k_bnparam<<<(5 * 128 + 255) / 256, 256, 0, stream>>>(gammas, betas, mean, var,
                                                       scale, shift, 5 * 128);
  k_wprep<<<(90112 + 255) / 256, 256, 0, stream>>>(W_in, Ws, W_out, wt_hi, wt_lo);

  const int gblocks = (N + 127) / 128;
  const int ablocks = (N + 3) / 4;

  // t0 = x @ W_in
  k_mgemm<128, false, false><<<gblocks, 256, 0, stream>>>(
      x, wt_hi, wt_lo, nullptr, nullptr, nullptr, t, N);

  const float* biases[5] = {b_in, bs, bs + 128, bs + 256, bs + 384};
  for (int l = 0; l < 4; ++l) {
    k_agg<<<ablocks, 256, 0, stream>>>(rowstart, counts, esrc, ecoef, t, dis,
                                       biases[l], agg, N);
    k_mgemm<128, true, false><<<gblocks, 256, 0, stream>>>(
        agg, wt_hi + (size_t)(l + 1) * 16384, wt_lo + (size_t)(l + 1) * 16384,
        scale + l * 128, shift + l * 128, nullptr, t, N);
  }
  k_agg<<<ablocks, 256, 0, stream>>>(rowstart, counts, esrc, ecoef, t, dis,
                                     biases[4], agg, N);
  k_mgemm<64, true, true><<<gblocks, 256, 0, stream>>>(
      agg, wt_hi + 81920, wt_lo + 81920, scale + 4 * 128, shift + 4 * 128,
      b_out, out, N);
}

// Round 5
// 484.253 us; speedup vs baseline: 1.5332x; 1.2034x over previous
//
#include <hip/hip_runtime.h>
#include <cstdint>

#define BN_EPS 1e-5f

typedef __bf16 bf16x8 __attribute__((ext_vector_type(8)));
typedef __bf16 bf16x4 __attribute__((ext_vector_type(4)));
typedef __bf16 bf16x2 __attribute__((ext_vector_type(2)));
typedef float f32x4 __attribute__((ext_vector_type(4)));

// ---------- CSR build ----------

__global__ __launch_bounds__(256) void k_count(const int* __restrict__ dstv,
                                               int* __restrict__ counts, int E) {
  int e = blockIdx.x * 256 + threadIdx.x;
  if (e < E) atomicAdd(counts + dstv[e], 1);
}

__global__ __launch_bounds__(256) void k_dis(const int* __restrict__ counts,
                                             float* __restrict__ dis, int N) {
  int i = blockIdx.x * 256 + threadIdx.x;
  if (i < N) dis[i] = rsqrtf((float)counts[i] + 1.0f);
}

// per-block (1024 elems) exclusive scan; block total -> bsum
__global__ __launch_bounds__(256) void k_scan1(const int* __restrict__ counts,
                                               int* __restrict__ rowstart,
                                               int* __restrict__ bsum, int N) {
  __shared__ int wsum[4];
  const int tid = threadIdx.x, lane = tid & 63, wv = tid >> 6;
  const int base = blockIdx.x * 1024 + tid * 4;
  int c[4];
#pragma unroll
  for (int j = 0; j < 4; ++j) {
    int idx = base + j;
    c[j] = (idx < N) ? counts[idx] : 0;
  }
  int s = c[0] + c[1] + c[2] + c[3];
  int x = s;  // inclusive wave scan
  for (int d = 1; d < 64; d <<= 1) {
    int y = __shfl_up(x, d);
    if (lane >= d) x += y;
  }
  if (lane == 63) wsum[wv] = x;
  __syncthreads();
  int woff = 0;
  for (int w = 0; w < wv; ++w) woff += wsum[w];
  int r = woff + x - s;
#pragma unroll
  for (int j = 0; j < 4; ++j) {
    int idx = base + j;
    if (idx < N) rowstart[idx] = r;
    r += c[j];
  }
  if (tid == 255) bsum[blockIdx.x] = woff + x;
}

__global__ __launch_bounds__(256) void k_scan2(const int* __restrict__ bsum,
                                               int* __restrict__ boff, int nb) {
  __shared__ int sm[256];
  const int tid = threadIdx.x;
  int v = (tid < nb) ? bsum[tid] : 0;
  sm[tid] = v;
  __syncthreads();
  for (int d = 1; d < 256; d <<= 1) {
    int y = (tid >= d) ? sm[tid - d] : 0;
    __syncthreads();
    sm[tid] += y;
    __syncthreads();
  }
  if (tid < nb) boff[tid] = sm[tid] - v;
}

__global__ __launch_bounds__(256) void k_fix(int* __restrict__ rowstart,
                                             const int* __restrict__ boff,
                                             int* __restrict__ cursor, int N) {
  int i = blockIdx.x * 256 + threadIdx.x;
  if (i < N) {
    int v = rowstart[i] + boff[i >> 10];
    rowstart[i] = v;
    cursor[i] = v;
  }
}

__global__ __launch_bounds__(256) void k_scatter(const int* __restrict__ src,
                                                 const int* __restrict__ dstv,
                                                 const float* __restrict__ dis,
                                                 int* __restrict__ cursor,
                                                 int* __restrict__ esrc,
                                                 float* __restrict__ ecoef, int E) {
  int e = blockIdx.x * 256 + threadIdx.x;
  if (e < E) {
    int s = src[e], d = dstv[e];
    int p = atomicAdd(cursor + d, 1);
    esrc[p] = s;
    ecoef[p] = dis[s] * dis[d];
  }
}

__global__ __launch_bounds__(256) void k_bnparam(const float* __restrict__ gamma,
                                                 const float* __restrict__ beta,
                                                 const float* __restrict__ mean,
                                                 const float* __restrict__ var,
                                                 float* __restrict__ scale,
                                                 float* __restrict__ shift, int n) {
  int i = blockIdx.x * 256 + threadIdx.x;
  if (i < n) {
    float s = gamma[i] * rsqrtf(var[i] + BN_EPS);
    scale[i] = s;
    shift[i] = beta[i] - mean[i] * s;
  }
}

// ---------- weight prep: transpose to [n][k] and split fp32 -> bf16 hi + lo ----------
// layout in wt_hi/wt_lo: layers 0..4 at l*16384 (128x128), final at 81920 (64x128)
__global__ __launch_bounds__(256) void k_wprep(const float* __restrict__ W_in,
                                               const float* __restrict__ Ws,
                                               const float* __restrict__ W_out,
                                               __bf16* __restrict__ wt_hi,
                                               __bf16* __restrict__ wt_lo) {
  int idx = blockIdx.x * 256 + threadIdx.x;
  float v;
  int dst;
  if (idx < 81920) {
    int l = idx >> 14, r = idx & 16383, k = r >> 7, n = r & 127;
    v = (l == 0) ? W_in[k * 128 + n] : Ws[(size_t)(l - 1) * 16384 + k * 128 + n];
    dst = l * 16384 + n * 128 + k;
  } else if (idx < 90112) {
    int r = idx - 81920, k = r >> 6, n = r & 63;
    v = W_out[k * 64 + n];
    dst = 81920 + n * 128 + k;
  } else {
    return;
  }
  __bf16 hi = (__bf16)v;
  float lof = v - (float)hi;
  wt_hi[dst] = hi;
  wt_lo[dst] = (__bf16)lof;
}

// ---------- MFMA GEMM (bf16 hi/lo split ~= fp32): out = act(in)[N,128] @ W ----------
// BM=128 rows/block, 256 threads = 4 waves; wave wv owns rows wv*32..wv*32+31 (2 rowtiles),
// all BNC columns (CT coltiles). A staged fp32->bf16 hi/lo in LDS (XOR swizzle), W chunk
// (32 k) staged per iter from precomputed transposed hi/lo bf16 weights.
// Non-FINAL: writes t (bf16). FINAL: writes fp32 out + bias.
template <int BNC, bool APPLY_BN, bool FINAL>
__global__ __launch_bounds__(256, 2) void k_mgemm(
    const float* __restrict__ in, const __bf16* __restrict__ wt_hi,
    const __bf16* __restrict__ wt_lo, const float* __restrict__ scale,
    const float* __restrict__ shift, const float* __restrict__ out_bias,
    float* __restrict__ outf, __bf16* __restrict__ outh, int N) {
  constexpr int CT = BNC / 16;
  __shared__ __align__(16) char smem[65536 + BNC * 128];
  char* const Abase = smem;          // [2 planes][128 rows][128 k] bf16, swizzled
  char* const Bbase = smem + 65536;  // [2 planes][BNC cols][32 k] bf16, swizzled

  const int tid = threadIdx.x;
  const int lane = tid & 63;
  const int wv = tid >> 6;
  const int lr = lane & 15;
  const int kg = lane >> 4;
  const int rowBase = blockIdx.x * 128;

  // ---- stage A: fp32 -> (bn+relu) -> bf16 hi/lo planes ----
  {
    const int kq = tid & 31;  // which float4 of the row (constant per thread)
    float4 sc4 = make_float4(0.f, 0.f, 0.f, 0.f), sh4 = sc4;
    if constexpr (APPLY_BN) {
      sc4 = *(const float4*)(scale + kq * 4);
      sh4 = *(const float4*)(shift + kq * 4);
    }
#pragma unroll
    for (int i = 0; i < 16; ++i) {
      const int row = (tid >> 5) + i * 8;
      const int grow = rowBase + row;
      float4 v = make_float4(0.f, 0.f, 0.f, 0.f);
      if (grow < N) v = *(const float4*)(in + (size_t)grow * 128 + kq * 4);
      if constexpr (APPLY_BN) {
        v.x = fmaxf(fmaf(v.x, sc4.x, sh4.x), 0.f);
        v.y = fmaxf(fmaf(v.y, sc4.y, sh4.y), 0.f);
        v.z = fmaxf(fmaf(v.z, sc4.z, sh4.z), 0.f);
        v.w = fmaxf(fmaf(v.w, sc4.w, sh4.w), 0.f);
      }
      bf16x4 hi, lo;
      hi[0] = (__bf16)v.x; lo[0] = (__bf16)(v.x - (float)hi[0]);
      hi[1] = (__bf16)v.y; lo[1] = (__bf16)(v.y - (float)hi[1]);
      hi[2] = (__bf16)v.z; lo[2] = (__bf16)(v.z - (float)hi[2]);
      hi[3] = (__bf16)v.w; lo[3] = (__bf16)(v.w - (float)hi[3]);
      int byte = row * 256 + kq * 8;
      byte ^= (row & 7) << 4;
      *(bf16x4*)(Abase + byte) = hi;
      *(bf16x4*)(Abase + 32768 + byte) = lo;
    }
  }

  f32x4 acc[2][CT] = {};

  for (int kc = 0; kc < 128; kc += 32) {
    __syncthreads();  // first iter: A staged; later: waves done reading prev W chunk
    // ---- stage W chunk (both planes) ----
#pragma unroll
    for (int hl = 0; hl < 2; ++hl) {
      const __bf16* wsrc = hl ? wt_lo : wt_hi;
#pragma unroll
      for (int p = 0; p < BNC / 64; ++p) {
        const int u = tid + p * 256;
        const int n = u >> 2, kslot = u & 3;
        uint4 v = *(const uint4*)(wsrc + (size_t)n * 128 + kc + kslot * 8);
        int byte = n * 64 + kslot * 16;
        byte ^= (n & 7) << 4;
        *(uint4*)(Bbase + hl * (BNC * 64) + byte) = v;
      }
    }
    __syncthreads();
    // ---- compute ----
    bf16x8 afr[2][2];  // [rowtile][hi/lo]
#pragma unroll
    for (int rt = 0; rt < 2; ++rt) {
      const int row = wv * 32 + rt * 16 + lr;
      int byte = row * 256 + kc * 2 + kg * 16;
      byte ^= (row & 7) << 4;
      afr[rt][0] = *(const bf16x8*)(Abase + byte);
      afr[rt][1] = *(const bf16x8*)(Abase + 32768 + byte);
    }
#pragma unroll
    for (int ct = 0; ct < CT; ++ct) {
      const int col = ct * 16 + lr;
      int byte = col * 64 + kg * 16;
      byte ^= (col & 7) << 4;
      bf16x8 bhi = *(const bf16x8*)(Bbase + byte);
      bf16x8 blo = *(const bf16x8*)(Bbase + BNC * 64 + byte);
#pragma unroll
      for (int rt = 0; rt < 2; ++rt) {
        acc[rt][ct] = __builtin_amdgcn_mfma_f32_16x16x32_bf16(afr[rt][0], bhi,
                                                              acc[rt][ct], 0, 0, 0);
        acc[rt][ct] = __builtin_amdgcn_mfma_f32_16x16x32_bf16(afr[rt][0], blo,
                                                              acc[rt][ct], 0, 0, 0);
        acc[rt][ct] = __builtin_amdgcn_mfma_f32_16x16x32_bf16(afr[rt][1], bhi,
                                                              acc[rt][ct], 0, 0, 0);
      }
    }
  }

  // ---- epilogue: C/D layout col=lane&15, row=(lane>>4)*4+j ----
  float ob[CT];
  if constexpr (FINAL) {
#pragma unroll
    for (int ct = 0; ct < CT; ++ct) ob[ct] = out_bias[ct * 16 + lr];
  }
#pragma unroll
  for (int rt = 0; rt < 2; ++rt) {
#pragma unroll
    for (int j = 0; j < 4; ++j) {
      const int row = rowBase + wv * 32 + rt * 16 + kg * 4 + j;
      if (row < N) {
#pragma unroll
        for (int ct = 0; ct < CT; ++ct) {
          const int col = ct * 16 + lr;
          if constexpr (FINAL) {
            outf[(size_t)row * BNC + col] = acc[rt][ct][j] + ob[ct];
          } else {
            outh[(size_t)row * BNC + col] = (__bf16)acc[rt][ct][j];
          }
        }
      }
    }
  }
}

// ---------- CSR gather: agg[d] = sum_e t[src_e]*coef_e + t[d]/deg + bias ----------
// t is bf16 (256B rows = 4 cache lines); agg stays fp32.
__global__ __launch_bounds__(256) void k_agg(const int* __restrict__ rowstart,
                                             const int* __restrict__ counts,
                                             const int* __restrict__ esrc,
                                             const float* __restrict__ ecoef,
                                             const __bf16* __restrict__ t,
                                             const float* __restrict__ dis,
                                             const float* __restrict__ bias,
                                             float* __restrict__ agg, int N) {
  const int lane = threadIdx.x & 63;
  const int wv = threadIdx.x >> 6;
  const int node = blockIdx.x * 4 + wv;
  if (node >= N) return;
  const int beg = rowstart[node];
  const int cnt = counts[node];
  const float dsq = dis[node] * dis[node];

  bf16x2 sv = *reinterpret_cast<const bf16x2*>(t + (size_t)node * 128 + lane * 2);
  float ax = (float)sv[0] * dsq;
  float ay = (float)sv[1] * dsq;

  int i = 0;
  for (; i + 4 <= cnt; i += 4) {
    const int s0 = esrc[beg + i + 0], s1 = esrc[beg + i + 1];
    const int s2 = esrc[beg + i + 2], s3 = esrc[beg + i + 3];
    const float c0 = ecoef[beg + i + 0], c1 = ecoef[beg + i + 1];
    const float c2 = ecoef[beg + i + 2], c3 = ecoef[beg + i + 3];
    const bf16x2 v0 = *reinterpret_cast<const bf16x2*>(t + (size_t)s0 * 128 + lane * 2);
    const bf16x2 v1 = *reinterpret_cast<const bf16x2*>(t + (size_t)s1 * 128 + lane * 2);
    const bf16x2 v2 = *reinterpret_cast<const bf16x2*>(t + (size_t)s2 * 128 + lane * 2);
    const bf16x2 v3 = *reinterpret_cast<const bf16x2*>(t + (size_t)s3 * 128 + lane * 2);
    ax = fmaf((float)v0[0], c0, ax); ay = fmaf((float)v0[1], c0, ay);
    ax = fmaf((float)v1[0], c1, ax); ay = fmaf((float)v1[1], c1, ay);
    ax = fmaf((float)v2[0], c2, ax); ay = fmaf((float)v2[1], c2, ay);
    ax = fmaf((float)v3[0], c3, ax); ay = fmaf((float)v3[1], c3, ay);
  }
  for (; i < cnt; ++i) {
    const int s0 = esrc[beg + i];
    const float c0 = ecoef[beg + i];
    const bf16x2 v0 = *reinterpret_cast<const bf16x2*>(t + (size_t)s0 * 128 + lane * 2);
    ax = fmaf((float)v0[0], c0, ax); ay = fmaf((float)v0[1], c0, ay);
  }
  float2 o;
  o.x = ax + bias[lane * 2 + 0];
  o.y = ay + bias[lane * 2 + 1];
  *reinterpret_cast<float2*>(agg + (size_t)node * 128 + lane * 2) = o;
}

// ---------- launch ----------
extern "C" void kernel_launch(void* const* d_in, const int* in_sizes, int n_in,
                              void* d_out, int out_size, void* d_ws, size_t ws_size,
                              hipStream_t stream) {
  const float* x      = (const float*)d_in[0];
  const int*   ei     = (const int*)d_in[1];
  const float* W_in   = (const float*)d_in[2];
  const float* b_in   = (const float*)d_in[3];
  const float* Ws     = (const float*)d_in[4];
  const float* bs     = (const float*)d_in[5];
  const float* gammas = (const float*)d_in[6];
  const float* betas  = (const float*)d_in[7];
  const float* mean   = (const float*)d_in[8];
  const float* var    = (const float*)d_in[9];
  const float* W_out  = (const float*)d_in[10];
  const float* b_out  = (const float*)d_in[11];
  float* out = (float*)d_out;

  const int N = in_sizes[0] / 128;
  const int E = in_sizes[1] / 2;
  const int* src = ei;
  const int* dst = ei + E;

  char* ws = (char*)d_ws;
  size_t off = 0;
  auto alloc = [&](size_t bytes) {
    void* p = ws + off;
    off = (off + bytes + 255) & ~255ULL;
    return p;
  };
  int*    counts   = (int*)alloc((size_t)N * 4);
  int*    rowstart = (int*)alloc((size_t)N * 4);
  int*    cursor   = (int*)alloc((size_t)N * 4);
  int*    bsum     = (int*)alloc(256 * 4);
  int*    boff     = (int*)alloc(256 * 4);
  float*  dis      = (float*)alloc((size_t)N * 4);
  float*  scale    = (float*)alloc(5 * 128 * 4);
  float*  shift    = (float*)alloc(5 * 128 * 4);
  __bf16* wt_hi    = (__bf16*)alloc(90112 * 2);
  __bf16* wt_lo    = (__bf16*)alloc(90112 * 2);
  int*    esrc     = (int*)alloc((size_t)E * 4);
  float*  ecoef    = (float*)alloc((size_t)E * 4);
  __bf16* t        = (__bf16*)alloc((size_t)N * 128 * 2);
  float*  agg      = (float*)alloc((size_t)N * 128 * 4);
  (void)ws_size;

  const int nb = (N + 1023) / 1024;

  hipMemsetAsync(counts, 0, (size_t)N * 4, stream);
  k_count<<<(E + 255) / 256, 256, 0, stream>>>(dst, counts, E);
  k_dis<<<(N + 255) / 256, 256, 0, stream>>>(counts, dis, N);
  k_scan1<<<nb, 256, 0, stream>>>(counts, rowstart, bsum, N);
  k_scan2<<<1, 256, 0, stream>>>(bsum, boff, nb);
  k_fix<<<(N + 255) / 256, 256, 0, stream>>>(rowstart, boff, cursor, N);
  k_scatter<<<(E + 255) / 256, 256, 0, stream>>>(src, dst, dis, cursor, esrc, ecoef, E);
  k_bnparam<<<(5 * 128 + 255) / 256, 256, 0, stream>>>(gammas, betas, mean, var,
                                                       scale, shift, 5 * 128);
  k_wprep<<<(90112 + 255) / 256, 256, 0, stream>>>(W_in, Ws, W_out, wt_hi, wt_lo);

  const int gblocks = (N + 127) / 128;
  const int ablocks = (N + 3) / 4;

  // t0 = x @ W_in  (bf16 out)
  k_mgemm<128, false, false><<<gblocks, 256, 0, stream>>>(
      x, wt_hi, wt_lo, nullptr, nullptr, nullptr, nullptr, t, N);

  const float* biases[5] = {b_in, bs, bs + 128, bs + 256, bs + 384};
  for (int l = 0; l < 4; ++l) {
    k_agg<<<ablocks, 256, 0, stream>>>(rowstart, counts, esrc, ecoef, t, dis,
                                       biases[l], agg, N);
    k_mgemm<128, true, false><<<gblocks, 256, 0, stream>>>(
        agg, wt_hi + (size_t)(l + 1) * 16384, wt_lo + (size_t)(l + 1) * 16384,
        scale + l * 128, shift + l * 128, nullptr, nullptr, t, N);
  }
  k_agg<<<ablocks, 256, 0, stream>>>(rowstart, counts, esrc, ecoef, t, dis,
                                     biases[4], agg, N);
  k_mgemm<64, true, true><<<gblocks, 256, 0, stream>>>(
      agg, wt_hi + 81920, wt_lo + 81920, scale + 4 * 128, shift + 4 * 128,
      b_out, out, nullptr, N);
}

// Round 6
// 430.165 us; speedup vs baseline: 1.7260x; 1.1257x over previous
//
#include <hip/hip_runtime.h>
#include <cstdint>

#define BN_EPS 1e-5f

typedef __bf16 bf16x8 __attribute__((ext_vector_type(8)));
typedef __bf16 bf16x4 __attribute__((ext_vector_type(4)));
typedef __bf16 bf16x2 __attribute__((ext_vector_type(2)));
typedef float f32x4 __attribute__((ext_vector_type(4)));

// ---------- CSR build ----------

__global__ __launch_bounds__(256) void k_count(const int* __restrict__ dstv,
                                               int* __restrict__ counts, int E) {
  int e = blockIdx.x * 256 + threadIdx.x;
  if (e < E) atomicAdd(counts + dstv[e], 1);
}

__global__ __launch_bounds__(256) void k_dis(const int* __restrict__ counts,
                                             float* __restrict__ dis, int N) {
  int i = blockIdx.x * 256 + threadIdx.x;
  if (i < N) dis[i] = rsqrtf((float)counts[i] + 1.0f);
}

// per-block (1024 elems) exclusive scan; block total -> bsum
__global__ __launch_bounds__(256) void k_scan1(const int* __restrict__ counts,
                                               int* __restrict__ rowstart,
                                               int* __restrict__ bsum, int N) {
  __shared__ int wsum[4];
  const int tid = threadIdx.x, lane = tid & 63, wv = tid >> 6;
  const int base = blockIdx.x * 1024 + tid * 4;
  int c[4];
#pragma unroll
  for (int j = 0; j < 4; ++j) {
    int idx = base + j;
    c[j] = (idx < N) ? counts[idx] : 0;
  }
  int s = c[0] + c[1] + c[2] + c[3];
  int x = s;  // inclusive wave scan
  for (int d = 1; d < 64; d <<= 1) {
    int y = __shfl_up(x, d);
    if (lane >= d) x += y;
  }
  if (lane == 63) wsum[wv] = x;
  __syncthreads();
  int woff = 0;
  for (int w = 0; w < wv; ++w) woff += wsum[w];
  int r = woff + x - s;
#pragma unroll
  for (int j = 0; j < 4; ++j) {
    int idx = base + j;
    if (idx < N) rowstart[idx] = r;
    r += c[j];
  }
  if (tid == 255) bsum[blockIdx.x] = woff + x;
}

__global__ __launch_bounds__(256) void k_scan2(const int* __restrict__ bsum,
                                               int* __restrict__ boff, int nb) {
  __shared__ int sm[256];
  const int tid = threadIdx.x;
  int v = (tid < nb) ? bsum[tid] : 0;
  sm[tid] = v;
  __syncthreads();
  for (int d = 1; d < 256; d <<= 1) {
    int y = (tid >= d) ? sm[tid - d] : 0;
    __syncthreads();
    sm[tid] += y;
    __syncthreads();
  }
  if (tid < nb) boff[tid] = sm[tid] - v;
}

__global__ __launch_bounds__(256) void k_fix(int* __restrict__ rowstart,
                                             const int* __restrict__ boff,
                                             int* __restrict__ cursor, int N) {
  int i = blockIdx.x * 256 + threadIdx.x;
  if (i < N) {
    int v = rowstart[i] + boff[i >> 10];
    rowstart[i] = v;
    cursor[i] = v;
  }
}

// edge record: {src, coef bits} — one 8B load per edge in k_agg
__global__ __launch_bounds__(256) void k_scatter(const int* __restrict__ src,
                                                 const int* __restrict__ dstv,
                                                 const float* __restrict__ dis,
                                                 int* __restrict__ cursor,
                                                 int2* __restrict__ edge, int E) {
  int e = blockIdx.x * 256 + threadIdx.x;
  if (e < E) {
    int s = src[e], d = dstv[e];
    int p = atomicAdd(cursor + d, 1);
    edge[p] = make_int2(s, __float_as_int(dis[s] * dis[d]));
  }
}

__global__ __launch_bounds__(256) void k_bnparam(const float* __restrict__ gamma,
                                                 const float* __restrict__ beta,
                                                 const float* __restrict__ mean,
                                                 const float* __restrict__ var,
                                                 float* __restrict__ scale,
                                                 float* __restrict__ shift, int n) {
  int i = blockIdx.x * 256 + threadIdx.x;
  if (i < n) {
    float s = gamma[i] * rsqrtf(var[i] + BN_EPS);
    scale[i] = s;
    shift[i] = beta[i] - mean[i] * s;
  }
}

// ---------- weight prep: transpose to [n][k] and split fp32 -> bf16 hi + lo ----------
// layout in wt_hi/wt_lo: layers 0..4 at l*16384 (128x128), final at 81920 (64x128)
__global__ __launch_bounds__(256) void k_wprep(const float* __restrict__ W_in,
                                               const float* __restrict__ Ws,
                                               const float* __restrict__ W_out,
                                               __bf16* __restrict__ wt_hi,
                                               __bf16* __restrict__ wt_lo) {
  int idx = blockIdx.x * 256 + threadIdx.x;
  float v;
  int dst;
  if (idx < 81920) {
    int l = idx >> 14, r = idx & 16383, k = r >> 7, n = r & 127;
    v = (l == 0) ? W_in[k * 128 + n] : Ws[(size_t)(l - 1) * 16384 + k * 128 + n];
    dst = l * 16384 + n * 128 + k;
  } else if (idx < 90112) {
    int r = idx - 81920, k = r >> 6, n = r & 63;
    v = W_out[k * 64 + n];
    dst = 81920 + n * 128 + k;
  } else {
    return;
  }
  __bf16 hi = (__bf16)v;
  float lof = v - (float)hi;
  wt_hi[dst] = hi;
  wt_lo[dst] = (__bf16)lof;
}

// ---------- MFMA GEMM: out = A[N,128] @ W  (A bf16; W bf16 hi/lo 2-term) ----------
// BM=128 rows/block, 256 threads = 4 waves; wave wv owns rows wv*32..wv*32+31
// (2 rowtiles), all BNC cols. A staged in LDS (XOR swizzle); W chunk (32 k)
// staged per iter. LDS = 32KB (A) + BNC*128 B (W) = 48KB @BNC=128 -> 3 blk/CU.
// A_FP32: input is fp32 (layer 0's x), rounded to bf16 on stage.
// FINAL: writes fp32 out + bias; else writes bf16 t.
template <int BNC, bool A_FP32, bool FINAL>
__global__ __launch_bounds__(256, 3) void k_mgemm(
    const void* __restrict__ in_v, const __bf16* __restrict__ wt_hi,
    const __bf16* __restrict__ wt_lo, const float* __restrict__ out_bias,
    float* __restrict__ outf, __bf16* __restrict__ outh, int N) {
  constexpr int CT = BNC / 16;
  __shared__ __align__(16) char smem[32768 + BNC * 128];
  char* const Abase = smem;          // [128 rows][128 k] bf16, swizzled
  char* const Bbase = smem + 32768;  // [2 planes][BNC cols][32 k] bf16, swizzled

  const int tid = threadIdx.x;
  const int lane = tid & 63;
  const int wv = tid >> 6;
  const int lr = lane & 15;
  const int kg = lane >> 4;
  const int rowBase = blockIdx.x * 128;

  // ---- stage A ----
  if constexpr (A_FP32) {
    const float* in = (const float*)in_v;
    const int kq = tid & 31;  // float4 slot within row
#pragma unroll
    for (int i = 0; i < 16; ++i) {
      const int row = (tid >> 5) + i * 8;
      const int grow = rowBase + row;
      float4 v = make_float4(0.f, 0.f, 0.f, 0.f);
      if (grow < N) v = *(const float4*)(in + (size_t)grow * 128 + kq * 4);
      bf16x4 h;
      h[0] = (__bf16)v.x; h[1] = (__bf16)v.y; h[2] = (__bf16)v.z; h[3] = (__bf16)v.w;
      int byte = row * 256 + kq * 8;
      byte ^= (row & 7) << 4;
      *(bf16x4*)(Abase + byte) = h;
    }
  } else {
    const __bf16* in = (const __bf16*)in_v;
    const int kq = tid & 15;  // 16B slot within row
#pragma unroll
    for (int i = 0; i < 8; ++i) {
      const int row = (tid >> 4) + i * 16;
      const int grow = rowBase + row;
      uint4 v = make_uint4(0, 0, 0, 0);
      if (grow < N) v = *(const uint4*)(in + (size_t)grow * 128 + kq * 8);
      int byte = row * 256 + kq * 16;
      byte ^= (row & 7) << 4;
      *(uint4*)(Abase + byte) = v;
    }
  }

  f32x4 acc[2][CT] = {};

  for (int kc = 0; kc < 128; kc += 32) {
    __syncthreads();  // first iter: A staged; later: done reading prev W chunk
    // ---- stage W chunk (both planes) ----
#pragma unroll
    for (int hl = 0; hl < 2; ++hl) {
      const __bf16* wsrc = hl ? wt_lo : wt_hi;
#pragma unroll
      for (int p = 0; p < BNC / 64; ++p) {
        const int u = tid + p * 256;
        const int n = u >> 2, kslot = u & 3;
        uint4 v = *(const uint4*)(wsrc + (size_t)n * 128 + kc + kslot * 8);
        int byte = n * 64 + kslot * 16;
        byte ^= (n & 7) << 4;
        *(uint4*)(Bbase + hl * (BNC * 64) + byte) = v;
      }
    }
    __syncthreads();
    // ---- compute ----
    bf16x8 afr[2];
#pragma unroll
    for (int rt = 0; rt < 2; ++rt) {
      const int row = wv * 32 + rt * 16 + lr;
      int byte = row * 256 + kc * 2 + kg * 16;
      byte ^= (row & 7) << 4;
      afr[rt] = *(const bf16x8*)(Abase + byte);
    }
#pragma unroll
    for (int ct = 0; ct < CT; ++ct) {
      const int col = ct * 16 + lr;
      int byte = col * 64 + kg * 16;
      byte ^= (col & 7) << 4;
      bf16x8 bhi = *(const bf16x8*)(Bbase + byte);
      bf16x8 blo = *(const bf16x8*)(Bbase + BNC * 64 + byte);
#pragma unroll
      for (int rt = 0; rt < 2; ++rt) {
        acc[rt][ct] = __builtin_amdgcn_mfma_f32_16x16x32_bf16(afr[rt], bhi,
                                                              acc[rt][ct], 0, 0, 0);
        acc[rt][ct] = __builtin_amdgcn_mfma_f32_16x16x32_bf16(afr[rt], blo,
                                                              acc[rt][ct], 0, 0, 0);
      }
    }
  }

  // ---- epilogue: C/D layout col=lane&15, row=(lane>>4)*4+j ----
  float ob[CT];
  if constexpr (FINAL) {
#pragma unroll
    for (int ct = 0; ct < CT; ++ct) ob[ct] = out_bias[ct * 16 + lr];
  }
#pragma unroll
  for (int rt = 0; rt < 2; ++rt) {
#pragma unroll
    for (int j = 0; j < 4; ++j) {
      const int row = rowBase + wv * 32 + rt * 16 + kg * 4 + j;
      if (row < N) {
#pragma unroll
        for (int ct = 0; ct < CT; ++ct) {
          const int col = ct * 16 + lr;
          if constexpr (FINAL) {
            outf[(size_t)row * BNC + col] = acc[rt][ct][j] + ob[ct];
          } else {
            outh[(size_t)row * BNC + col] = (__bf16)acc[rt][ct][j];
          }
        }
      }
    }
  }
}

// ---------- CSR gather + BN + ReLU:
// h[d] = relu(scale*(sum_e t[src_e]*coef_e + t[d]/deg + bias) + shift), bf16 out
__global__ __launch_bounds__(256) void k_agg(const int* __restrict__ rowstart,
                                             const int* __restrict__ counts,
                                             const int2* __restrict__ edge,
                                             const __bf16* __restrict__ t,
                                             const float* __restrict__ dis,
                                             const float* __restrict__ bias,
                                             const float* __restrict__ scale,
                                             const float* __restrict__ shift,
                                             __bf16* __restrict__ h, int N) {
  const int lane = threadIdx.x & 63;
  const int wv = threadIdx.x >> 6;
  const int node = blockIdx.x * 4 + wv;
  if (node >= N) return;
  const int beg = rowstart[node];
  const int cnt = counts[node];
  const float dsq = dis[node] * dis[node];

  bf16x2 sv = *reinterpret_cast<const bf16x2*>(t + (size_t)node * 128 + lane * 2);
  float ax = (float)sv[0] * dsq;
  float ay = (float)sv[1] * dsq;

  const int2* ed = edge + beg;
  int i = 0;
  for (; i + 4 <= cnt; i += 4) {
    const int2 e0 = ed[i + 0], e1 = ed[i + 1], e2 = ed[i + 2], e3 = ed[i + 3];
    const float c0 = __int_as_float(e0.y), c1 = __int_as_float(e1.y);
    const float c2 = __int_as_float(e2.y), c3 = __int_as_float(e3.y);
    const bf16x2 v0 = *reinterpret_cast<const bf16x2*>(t + (size_t)e0.x * 128 + lane * 2);
    const bf16x2 v1 = *reinterpret_cast<const bf16x2*>(t + (size_t)e1.x * 128 + lane * 2);
    const bf16x2 v2 = *reinterpret_cast<const bf16x2*>(t + (size_t)e2.x * 128 + lane * 2);
    const bf16x2 v3 = *reinterpret_cast<const bf16x2*>(t + (size_t)e3.x * 128 + lane * 2);
    ax = fmaf((float)v0[0], c0, ax); ay = fmaf((float)v0[1], c0, ay);
    ax = fmaf((float)v1[0], c1, ax); ay = fmaf((float)v1[1], c1, ay);
    ax = fmaf((float)v2[0], c2, ax); ay = fmaf((float)v2[1], c2, ay);
    ax = fmaf((float)v3[0], c3, ax); ay = fmaf((float)v3[1], c3, ay);
  }
  for (; i < cnt; ++i) {
    const int2 e0 = ed[i];
    const float c0 = __int_as_float(e0.y);
    const bf16x2 v0 = *reinterpret_cast<const bf16x2*>(t + (size_t)e0.x * 128 + lane * 2);
    ax = fmaf((float)v0[0], c0, ax); ay = fmaf((float)v0[1], c0, ay);
  }
  ax += bias[lane * 2 + 0];
  ay += bias[lane * 2 + 1];
  ax = fmaxf(fmaf(ax, scale[lane * 2 + 0], shift[lane * 2 + 0]), 0.f);
  ay = fmaxf(fmaf(ay, scale[lane * 2 + 1], shift[lane * 2 + 1]), 0.f);
  bf16x2 o;
  o[0] = (__bf16)ax;
  o[1] = (__bf16)ay;
  *reinterpret_cast<bf16x2*>(h + (size_t)node * 128 + lane * 2) = o;
}

// ---------- launch ----------
extern "C" void kernel_launch(void* const* d_in, const int* in_sizes, int n_in,
                              void* d_out, int out_size, void* d_ws, size_t ws_size,
                              hipStream_t stream) {
  const float* x      = (const float*)d_in[0];
  const int*   ei     = (const int*)d_in[1];
  const float* W_in   = (const float*)d_in[2];
  const float* b_in   = (const float*)d_in[3];
  const float* Ws     = (const float*)d_in[4];
  const float* bs     = (const float*)d_in[5];
  const float* gammas = (const float*)d_in[6];
  const float* betas  = (const float*)d_in[7];
  const float* mean   = (const float*)d_in[8];
  const float* var    = (const float*)d_in[9];
  const float* W_out  = (const float*)d_in[10];
  const float* b_out  = (const float*)d_in[11];
  float* out = (float*)d_out;

  const int N = in_sizes[0] / 128;
  const int E = in_sizes[1] / 2;
  const int* src = ei;
  const int* dst = ei + E;

  char* ws = (char*)d_ws;
  size_t off = 0;
  auto alloc = [&](size_t bytes) {
    void* p = ws + off;
    off = (off + bytes + 255) & ~255ULL;
    return p;
  };
  int*    counts   = (int*)alloc((size_t)N * 4);
  int*    rowstart = (int*)alloc((size_t)N * 4);
  int*    cursor   = (int*)alloc((size_t)N * 4);
  int*    bsum     = (int*)alloc(256 * 4);
  int*    boff     = (int*)alloc(256 * 4);
  float*  dis      = (float*)alloc((size_t)N * 4);
  float*  scale    = (float*)alloc(5 * 128 * 4);
  float*  shift    = (float*)alloc(5 * 128 * 4);
  __bf16* wt_hi    = (__bf16*)alloc(90112 * 2);
  __bf16* wt_lo    = (__bf16*)alloc(90112 * 2);
  int2*   edge     = (int2*)alloc((size_t)E * 8);
  __bf16* t        = (__bf16*)alloc((size_t)N * 128 * 2);
  __bf16* h        = (__bf16*)alloc((size_t)N * 128 * 2);
  (void)ws_size;

  const int nb = (N + 1023) / 1024;

  hipMemsetAsync(counts, 0, (size_t)N * 4, stream);
  k_count<<<(E + 255) / 256, 256, 0, stream>>>(dst, counts, E);
  k_dis<<<(N + 255) / 256, 256, 0, stream>>>(counts, dis, N);
  k_scan1<<<nb, 256, 0, stream>>>(counts, rowstart, bsum, N);
  k_scan2<<<1, 256, 0, stream>>>(bsum, boff, nb);
  k_fix<<<(N + 255) / 256, 256, 0, stream>>>(rowstart, boff, cursor, N);
  k_scatter<<<(E + 255) / 256, 256, 0, stream>>>(src, dst, dis, cursor, edge, E);
  k_bnparam<<<(5 * 128 + 255) / 256, 256, 0, stream>>>(gammas, betas, mean, var,
                                                       scale, shift, 5 * 128);
  k_wprep<<<(90112 + 255) / 256, 256, 0, stream>>>(W_in, Ws, W_out, wt_hi, wt_lo);

  const int gblocks = (N + 127) / 128;
  const int ablocks = (N + 3) / 4;

  // t0 = bf16(x) @ W_in
  k_mgemm<128, true, false><<<gblocks, 256, 0, stream>>>(
      x, wt_hi, wt_lo, nullptr, nullptr, t, N);

  const float* biases[5] = {b_in, bs, bs + 128, bs + 256, bs + 384};
  for (int l = 0; l < 4; ++l) {
    k_agg<<<ablocks, 256, 0, stream>>>(rowstart, counts, edge, t, dis, biases[l],
                                       scale + l * 128, shift + l * 128, h, N);
    k_mgemm<128, false, false><<<gblocks, 256, 0, stream>>>(
        h, wt_hi + (size_t)(l + 1) * 16384, wt_lo + (size_t)(l + 1) * 16384,
        nullptr, nullptr, t, N);
  }
  k_agg<<<ablocks, 256, 0, stream>>>(rowstart, counts, edge, t, dis, biases[4],
                                     scale + 4 * 128, shift + 4 * 128, h, N);
  k_mgemm<64, false, true><<<gblocks, 256, 0, stream>>>(
      h, wt_hi + 81920, wt_lo + 81920, b_out, out, nullptr, N);
}

// Round 7
// 372.627 us; speedup vs baseline: 1.9926x; 1.1544x over previous
//
#include <hip/hip_runtime.h>
#include <cstdint>

#define BN_EPS 1e-5f

typedef __bf16 bf16x8 __attribute__((ext_vector_type(8)));
typedef __bf16 bf16x4 __attribute__((ext_vector_type(4)));
typedef __bf16 bf16x2 __attribute__((ext_vector_type(2)));
typedef float f32x4 __attribute__((ext_vector_type(4)));

// ---------- CSR build ----------

__global__ __launch_bounds__(256) void k_count(const int* __restrict__ dstv,
                                               int* __restrict__ counts, int E) {
  int e = blockIdx.x * 256 + threadIdx.x;
  if (e < E) atomicAdd(counts + dstv[e], 1);
}

__global__ __launch_bounds__(256) void k_dis(const int* __restrict__ counts,
                                             float* __restrict__ dis, int N) {
  int i = blockIdx.x * 256 + threadIdx.x;
  if (i < N) dis[i] = rsqrtf((float)counts[i] + 1.0f);
}

// per-block (1024 elems) exclusive scan; block total -> bsum
__global__ __launch_bounds__(256) void k_scan1(const int* __restrict__ counts,
                                               int* __restrict__ rowstart,
                                               int* __restrict__ bsum, int N) {
  __shared__ int wsum[4];
  const int tid = threadIdx.x, lane = tid & 63, wv = tid >> 6;
  const int base = blockIdx.x * 1024 + tid * 4;
  int c[4];
#pragma unroll
  for (int j = 0; j < 4; ++j) {
    int idx = base + j;
    c[j] = (idx < N) ? counts[idx] : 0;
  }
  int s = c[0] + c[1] + c[2] + c[3];
  int x = s;  // inclusive wave scan
  for (int d = 1; d < 64; d <<= 1) {
    int y = __shfl_up(x, d);
    if (lane >= d) x += y;
  }
  if (lane == 63) wsum[wv] = x;
  __syncthreads();
  int woff = 0;
  for (int w = 0; w < wv; ++w) woff += wsum[w];
  int r = woff + x - s;
#pragma unroll
  for (int j = 0; j < 4; ++j) {
    int idx = base + j;
    if (idx < N) rowstart[idx] = r;
    r += c[j];
  }
  if (tid == 255) bsum[blockIdx.x] = woff + x;
}

__global__ __launch_bounds__(256) void k_scan2(const int* __restrict__ bsum,
                                               int* __restrict__ boff, int nb) {
  __shared__ int sm[256];
  const int tid = threadIdx.x;
  int v = (tid < nb) ? bsum[tid] : 0;
  sm[tid] = v;
  __syncthreads();
  for (int d = 1; d < 256; d <<= 1) {
    int y = (tid >= d) ? sm[tid - d] : 0;
    __syncthreads();
    sm[tid] += y;
    __syncthreads();
  }
  if (tid < nb) boff[tid] = sm[tid] - v;
}

__global__ __launch_bounds__(256) void k_fix(int* __restrict__ rowstart,
                                             const int* __restrict__ boff,
                                             int* __restrict__ cursor, int N) {
  int i = blockIdx.x * 256 + threadIdx.x;
  if (i < N) {
    int v = rowstart[i] + boff[i >> 10];
    rowstart[i] = v;
    cursor[i] = v;
  }
}

// edge record: {src, coef bits} — one 8B load per edge in k_agg
__global__ __launch_bounds__(256) void k_scatter(const int* __restrict__ src,
                                                 const int* __restrict__ dstv,
                                                 const float* __restrict__ dis,
                                                 int* __restrict__ cursor,
                                                 int2* __restrict__ edge, int E) {
  int e = blockIdx.x * 256 + threadIdx.x;
  if (e < E) {
    int s = src[e], d = dstv[e];
    int p = atomicAdd(cursor + d, 1);
    edge[p] = make_int2(s, __float_as_int(dis[s] * dis[d]));
  }
}

__global__ __launch_bounds__(256) void k_bnparam(const float* __restrict__ gamma,
                                                 const float* __restrict__ beta,
                                                 const float* __restrict__ mean,
                                                 const float* __restrict__ var,
                                                 float* __restrict__ scale,
                                                 float* __restrict__ shift, int n) {
  int i = blockIdx.x * 256 + threadIdx.x;
  if (i < n) {
    float s = gamma[i] * rsqrtf(var[i] + BN_EPS);
    scale[i] = s;
    shift[i] = beta[i] - mean[i] * s;
  }
}

// ---------- weight prep: fp32 W -> bf16 hi/lo in MFMA FRAGMENT ORDER ----------
// Per layer, per kc_i(4) x plane(2) x ct(CT): a 1KB block of 64 lanes x 16B.
// Lane (lr=lane&15, kg=lane>>4) holds W[k0..k0+8)[ct*16+lr], k0=kc_i*32+kg*8.
// Layers 0..4: CT=8, 64KB each at l*65536. Final: CT=4, 32KB at 327680.
__global__ __launch_bounds__(256) void k_wprep(const float* __restrict__ W_in,
                                               const float* __restrict__ Ws,
                                               const float* __restrict__ W_out,
                                               __bf16* __restrict__ wfrag) {
  const int idx = blockIdx.x * 256 + threadIdx.x;
  if (idx >= 11264) return;
  int l, r, CT;
  if (idx < 10240) { l = idx >> 11; r = idx & 2047; CT = 8; }
  else             { l = 5; r = idx - 10240; CT = 4; }
  const int lane = r & 63;
  const int rr = r >> 6;
  const int ct = rr % CT;
  const int kc_i = rr / CT;
  const int lr = lane & 15, kg = lane >> 4;
  const int col = ct * 16 + lr;
  const int k0 = kc_i * 32 + kg * 8;
  const float* Wsrc;
  int ncols;
  if (l == 0)      { Wsrc = W_in; ncols = 128; }
  else if (l <= 4) { Wsrc = Ws + (size_t)(l - 1) * 16384; ncols = 128; }
  else             { Wsrc = W_out; ncols = 64; }
  bf16x8 hi, lo;
#pragma unroll
  for (int j = 0; j < 8; ++j) {
    float v = Wsrc[(size_t)(k0 + j) * ncols + col];
    __bf16 h = (__bf16)v;
    hi[j] = h;
    lo[j] = (__bf16)(v - (float)h);
  }
  const size_t lbase = (l < 5) ? (size_t)l * 65536 : (size_t)327680;
  char* outp = (char*)wfrag + lbase;
  *(bf16x8*)(outp + ((size_t)(kc_i * 2 + 0) * CT + ct) * 1024 + lane * 16) = hi;
  *(bf16x8*)(outp + ((size_t)(kc_i * 2 + 1) * CT + ct) * 1024 + lane * 16) = lo;
}

// ---------- MFMA GEMM: out = A[N,128] @ W  (A bf16 via LDS; B direct from L2) ----------
// BM=128 rows/block, 256 threads = 4 waves; wave wv owns rows wv*32..wv*32+31.
// A staged in LDS (XOR swizzle), ONE barrier; B fragments read fragment-ordered
// from global (L2-hot), no W LDS, no per-chunk barriers. LDS 32KB -> 4 blk/CU.
template <int BNC, bool A_FP32, bool FINAL>
__global__ __launch_bounds__(256, 4) void k_mgemm(
    const void* __restrict__ in_v, const __bf16* __restrict__ wfrag,
    const float* __restrict__ out_bias, float* __restrict__ outf,
    __bf16* __restrict__ outh, int N) {
  constexpr int CT = BNC / 16;
  __shared__ __align__(16) char Abase[32768];  // [128 rows][128 k] bf16, swizzled

  const int tid = threadIdx.x;
  const int lane = tid & 63;
  const int wv = tid >> 6;
  const int lr = lane & 15;
  const int kg = lane >> 4;
  const int rowBase = blockIdx.x * 128;

  // ---- stage A ----
  if constexpr (A_FP32) {
    const float* in = (const float*)in_v;
    const int kq = tid & 31;  // float4 slot within row
#pragma unroll
    for (int i = 0; i < 16; ++i) {
      const int row = (tid >> 5) + i * 8;
      const int grow = rowBase + row;
      float4 v = make_float4(0.f, 0.f, 0.f, 0.f);
      if (grow < N) v = *(const float4*)(in + (size_t)grow * 128 + kq * 4);
      bf16x4 h;
      h[0] = (__bf16)v.x; h[1] = (__bf16)v.y; h[2] = (__bf16)v.z; h[3] = (__bf16)v.w;
      int byte = row * 256 + kq * 8;
      byte ^= (row & 7) << 4;
      *(bf16x4*)(Abase + byte) = h;
    }
  } else {
    const __bf16* in = (const __bf16*)in_v;
    const int kq = tid & 15;  // 16B slot within row
#pragma unroll
    for (int i = 0; i < 8; ++i) {
      const int row = (tid >> 4) + i * 16;
      const int grow = rowBase + row;
      uint4 v = make_uint4(0, 0, 0, 0);
      if (grow < N) v = *(const uint4*)(in + (size_t)grow * 128 + kq * 8);
      int byte = row * 256 + kq * 16;
      byte ^= (row & 7) << 4;
      *(uint4*)(Abase + byte) = v;
    }
  }
  __syncthreads();

  f32x4 acc[2][CT] = {};

#pragma unroll
  for (int kc_i = 0; kc_i < 4; ++kc_i) {
    bf16x8 afr[2];
#pragma unroll
    for (int rt = 0; rt < 2; ++rt) {
      const int row = wv * 32 + rt * 16 + lr;
      int byte = row * 256 + kc_i * 64 + kg * 16;
      byte ^= (row & 7) << 4;
      afr[rt] = *(const bf16x8*)(Abase + byte);
    }
    const char* wk = (const char*)wfrag + (size_t)kc_i * (2 * CT * 1024) +
                     (size_t)lane * 16;
#pragma unroll
    for (int ct = 0; ct < CT; ++ct) {
      bf16x8 bhi = *(const bf16x8*)(wk + ct * 1024);
      bf16x8 blo = *(const bf16x8*)(wk + (CT + ct) * 1024);
#pragma unroll
      for (int rt = 0; rt < 2; ++rt) {
        acc[rt][ct] = __builtin_amdgcn_mfma_f32_16x16x32_bf16(afr[rt], bhi,
                                                              acc[rt][ct], 0, 0, 0);
        acc[rt][ct] = __builtin_amdgcn_mfma_f32_16x16x32_bf16(afr[rt], blo,
                                                              acc[rt][ct], 0, 0, 0);
      }
    }
  }

  // ---- epilogue: C/D layout col=lane&15, row=(lane>>4)*4+j ----
  float ob[CT];
  if constexpr (FINAL) {
#pragma unroll
    for (int ct = 0; ct < CT; ++ct) ob[ct] = out_bias[ct * 16 + lr];
  }
#pragma unroll
  for (int rt = 0; rt < 2; ++rt) {
#pragma unroll
    for (int j = 0; j < 4; ++j) {
      const int row = rowBase + wv * 32 + rt * 16 + kg * 4 + j;
      if (row < N) {
#pragma unroll
        for (int ct = 0; ct < CT; ++ct) {
          const int col = ct * 16 + lr;
          if constexpr (FINAL) {
            outf[(size_t)row * BNC + col] = acc[rt][ct][j] + ob[ct];
          } else {
            outh[(size_t)row * BNC + col] = (__bf16)acc[rt][ct][j];
          }
        }
      }
    }
  }
}

// ---------- CSR gather + BN + ReLU, burst-issue:
// h[d] = relu(scale*(sum_e t[src_e]*coef_e + t[d]/deg + bias) + shift), bf16 out.
// Edge records loaded lane-parallel (1 coalesced load covers <=64 edges), then
// readlane-broadcast so all gathers issue independently (one latency exposure).
__global__ __launch_bounds__(256) void k_agg(const int* __restrict__ rowstart,
                                             const int* __restrict__ counts,
                                             const int2* __restrict__ edge,
                                             const __bf16* __restrict__ t,
                                             const float* __restrict__ dis,
                                             const float* __restrict__ bias,
                                             const float* __restrict__ scale,
                                             const float* __restrict__ shift,
                                             __bf16* __restrict__ h, int N) {
  const int lane = threadIdx.x & 63;
  const int wv = threadIdx.x >> 6;
  const int node = blockIdx.x * 4 + wv;
  if (node >= N) return;
  const int beg = rowstart[node];
  const int cnt = counts[node];
  const float dn = dis[node];
  const float dsq = dn * dn;

  // self term (issued first, independent)
  bf16x2 sv = *reinterpret_cast<const bf16x2*>(t + (size_t)node * 128 + lane * 2);

  // lane-parallel edge records; pad with {row0, coef 0} (safe, adds 0)
  int2 rec = make_int2(0, 0);
  if (lane < cnt) rec = edge[beg + lane];

  float ax = (float)sv[0] * dsq;
  float ay = (float)sv[1] * dsq;

  const int m = cnt < 64 ? cnt : 64;
  const int rounds = (m + 7) >> 3;
  for (int r = 0; r < rounds; ++r) {
    const int base = r * 8;
#pragma unroll
    for (int u = 0; u < 8; ++u) {
      const int s = __builtin_amdgcn_readlane(rec.x, base + u);
      const float c = __int_as_float(__builtin_amdgcn_readlane(rec.y, base + u));
      const bf16x2 v =
          *reinterpret_cast<const bf16x2*>(t + (size_t)s * 128 + lane * 2);
      ax = fmaf((float)v[0], c, ax);
      ay = fmaf((float)v[1], c, ay);
    }
  }
  // rare overflow (degree > 64)
  for (int i = 64; i < cnt; ++i) {
    const int2 e0 = edge[beg + i];
    const float c0 = __int_as_float(e0.y);
    const bf16x2 v0 =
        *reinterpret_cast<const bf16x2*>(t + (size_t)e0.x * 128 + lane * 2);
    ax = fmaf((float)v0[0], c0, ax);
    ay = fmaf((float)v0[1], c0, ay);
  }

  ax += bias[lane * 2 + 0];
  ay += bias[lane * 2 + 1];
  ax = fmaxf(fmaf(ax, scale[lane * 2 + 0], shift[lane * 2 + 0]), 0.f);
  ay = fmaxf(fmaf(ay, scale[lane * 2 + 1], shift[lane * 2 + 1]), 0.f);
  bf16x2 o;
  o[0] = (__bf16)ax;
  o[1] = (__bf16)ay;
  *reinterpret_cast<bf16x2*>(h + (size_t)node * 128 + lane * 2) = o;
}

// ---------- launch ----------
extern "C" void kernel_launch(void* const* d_in, const int* in_sizes, int n_in,
                              void* d_out, int out_size, void* d_ws, size_t ws_size,
                              hipStream_t stream) {
  const float* x      = (const float*)d_in[0];
  const int*   ei     = (const int*)d_in[1];
  const float* W_in   = (const float*)d_in[2];
  const float* b_in   = (const float*)d_in[3];
  const float* Ws     = (const float*)d_in[4];
  const float* bs     = (const float*)d_in[5];
  const float* gammas = (const float*)d_in[6];
  const float* betas  = (const float*)d_in[7];
  const float* mean   = (const float*)d_in[8];
  const float* var    = (const float*)d_in[9];
  const float* W_out  = (const float*)d_in[10];
  const float* b_out  = (const float*)d_in[11];
  float* out = (float*)d_out;

  const int N = in_sizes[0] / 128;
  const int E = in_sizes[1] / 2;
  const int* src = ei;
  const int* dst = ei + E;

  char* ws = (char*)d_ws;
  size_t off = 0;
  auto alloc = [&](size_t bytes) {
    void* p = ws + off;
    off = (off + bytes + 255) & ~255ULL;
    return p;
  };
  int*    counts   = (int*)alloc((size_t)N * 4);
  int*    rowstart = (int*)alloc((size_t)N * 4);
  int*    cursor   = (int*)alloc((size_t)N * 4);
  int*    bsum     = (int*)alloc(256 * 4);
  int*    boff     = (int*)alloc(256 * 4);
  float*  dis      = (float*)alloc((size_t)N * 4);
  float*  scale    = (float*)alloc(5 * 128 * 4);
  float*  shift    = (float*)alloc(5 * 128 * 4);
  __bf16* wfrag    = (__bf16*)alloc(360448);  // 5*64KB + 32KB fragment-ordered W
  int2*   edge     = (int2*)alloc((size_t)E * 8);
  __bf16* t        = (__bf16*)alloc((size_t)N * 128 * 2);
  __bf16* h        = (__bf16*)alloc((size_t)N * 128 * 2);
  (void)ws_size;

  const int nb = (N + 1023) / 1024;

  hipMemsetAsync(counts, 0, (size_t)N * 4, stream);
  k_count<<<(E + 255) / 256, 256, 0, stream>>>(dst, counts, E);
  k_dis<<<(N + 255) / 256, 256, 0, stream>>>(counts, dis, N);
  k_scan1<<<nb, 256, 0, stream>>>(counts, rowstart, bsum, N);
  k_scan2<<<1, 256, 0, stream>>>(bsum, boff, nb);
  k_fix<<<(N + 255) / 256, 256, 0, stream>>>(rowstart, boff, cursor, N);
  k_scatter<<<(E + 255) / 256, 256, 0, stream>>>(src, dst, dis, cursor, edge, E);
  k_bnparam<<<(5 * 128 + 255) / 256, 256, 0, stream>>>(gammas, betas, mean, var,
                                                       scale, shift, 5 * 128);
  k_wprep<<<44, 256, 0, stream>>>(W_in, Ws, W_out, wfrag);

  const int gblocks = (N + 127) / 128;
  const int ablocks = (N + 3) / 4;

  // t0 = bf16(x) @ W_in
  k_mgemm<128, true, false><<<gblocks, 256, 0, stream>>>(
      x, wfrag, nullptr, nullptr, t, N);

  const float* biases[5] = {b_in, bs, bs + 128, bs + 256, bs + 384};
  for (int l = 0; l < 4; ++l) {
    k_agg<<<ablocks, 256, 0, stream>>>(rowstart, counts, edge, t, dis, biases[l],
                                       scale + l * 128, shift + l * 128, h, N);
    k_mgemm<128, false, false><<<gblocks, 256, 0, stream>>>(
        h, wfrag + (size_t)(l + 1) * 32768, nullptr, nullptr, t, N);
  }
  k_agg<<<ablocks, 256, 0, stream>>>(rowstart, counts, edge, t, dis, biases[4],
                                     scale + 4 * 128, shift + 4 * 128, h, N);
  k_mgemm<64, false, true><<<gblocks, 256, 0, stream>>>(
      h, wfrag + 163840, b_out, out, nullptr, N);
}

// Round 8
// 354.180 us; speedup vs baseline: 2.0963x; 1.0521x over previous
//
#include <hip/hip_runtime.h>
#include <cstdint>

#define BN_EPS 1e-5f

typedef __bf16 bf16x8 __attribute__((ext_vector_type(8)));
typedef __bf16 bf16x4 __attribute__((ext_vector_type(4)));
typedef __bf16 bf16x2 __attribute__((ext_vector_type(2)));
typedef float f32x4 __attribute__((ext_vector_type(4)));

// ---------- CSR build ----------

// count in-degree AND record each edge's rank within its dst list
__global__ __launch_bounds__(256) void k_count(const int* __restrict__ dstv,
                                               int* __restrict__ counts,
                                               int* __restrict__ rank, int E) {
  int e = blockIdx.x * 256 + threadIdx.x;
  if (e < E) rank[e] = atomicAdd(counts + dstv[e], 1);
}

__global__ __launch_bounds__(256) void k_dis(const int* __restrict__ counts,
                                             float* __restrict__ dis, int N) {
  int i = blockIdx.x * 256 + threadIdx.x;
  if (i < N) dis[i] = rsqrtf((float)counts[i] + 1.0f);
}

// per-block (1024 elems) exclusive scan; block total -> bsum
__global__ __launch_bounds__(256) void k_scan1(const int* __restrict__ counts,
                                               int* __restrict__ rowstart,
                                               int* __restrict__ bsum, int N) {
  __shared__ int wsum[4];
  const int tid = threadIdx.x, lane = tid & 63, wv = tid >> 6;
  const int base = blockIdx.x * 1024 + tid * 4;
  int c[4];
#pragma unroll
  for (int j = 0; j < 4; ++j) {
    int idx = base + j;
    c[j] = (idx < N) ? counts[idx] : 0;
  }
  int s = c[0] + c[1] + c[2] + c[3];
  int x = s;  // inclusive wave scan
  for (int d = 1; d < 64; d <<= 1) {
    int y = __shfl_up(x, d);
    if (lane >= d) x += y;
  }
  if (lane == 63) wsum[wv] = x;
  __syncthreads();
  int woff = 0;
  for (int w = 0; w < wv; ++w) woff += wsum[w];
  int r = woff + x - s;
#pragma unroll
  for (int j = 0; j < 4; ++j) {
    int idx = base + j;
    if (idx < N) rowstart[idx] = r;
    r += c[j];
  }
  if (tid == 255) bsum[blockIdx.x] = woff + x;
}

__global__ __launch_bounds__(256) void k_scan2(const int* __restrict__ bsum,
                                               int* __restrict__ boff, int nb) {
  __shared__ int sm[256];
  const int tid = threadIdx.x;
  int v = (tid < nb) ? bsum[tid] : 0;
  sm[tid] = v;
  __syncthreads();
  for (int d = 1; d < 256; d <<= 1) {
    int y = (tid >= d) ? sm[tid - d] : 0;
    __syncthreads();
    sm[tid] += y;
    __syncthreads();
  }
  if (tid < nb) boff[tid] = sm[tid] - v;
}

__global__ __launch_bounds__(256) void k_fix(int* __restrict__ rowstart,
                                             const int* __restrict__ boff, int N) {
  int i = blockIdx.x * 256 + threadIdx.x;
  if (i < N) rowstart[i] += boff[i >> 10];
}

// atomic-free placement: esrc[rowstart[dst] + rank] = src
__global__ __launch_bounds__(256) void k_scatter(const int* __restrict__ src,
                                                 const int* __restrict__ dstv,
                                                 const int* __restrict__ rowstart,
                                                 const int* __restrict__ rank,
                                                 int* __restrict__ esrc, int E) {
  int e = blockIdx.x * 256 + threadIdx.x;
  if (e < E) esrc[rowstart[dstv[e]] + rank[e]] = src[e];
}

__global__ __launch_bounds__(256) void k_bnparam(const float* __restrict__ gamma,
                                                 const float* __restrict__ beta,
                                                 const float* __restrict__ mean,
                                                 const float* __restrict__ var,
                                                 float* __restrict__ scale,
                                                 float* __restrict__ shift, int n) {
  int i = blockIdx.x * 256 + threadIdx.x;
  if (i < n) {
    float s = gamma[i] * rsqrtf(var[i] + BN_EPS);
    scale[i] = s;
    shift[i] = beta[i] - mean[i] * s;
  }
}

// zero pad row N of t (gather target for padded lanes)
__global__ __launch_bounds__(64) void k_zrow(__bf16* __restrict__ t, int N) {
  bf16x2 z;
  z[0] = (__bf16)0.f;
  z[1] = (__bf16)0.f;
  *reinterpret_cast<bf16x2*>(t + (size_t)N * 128 + threadIdx.x * 2) = z;
}

// ---------- weight prep: fp32 W -> bf16 hi/lo in MFMA FRAGMENT ORDER ----------
// Per layer, per kc_i(4) x plane(2) x ct(CT): a 1KB block of 64 lanes x 16B.
// Lane (lr=lane&15, kg=lane>>4) holds W[k0..k0+8)[ct*16+lr], k0=kc_i*32+kg*8.
// Layers 0..4: CT=8, 64KB each at l*65536. Final: CT=4, 32KB at 327680.
__global__ __launch_bounds__(256) void k_wprep(const float* __restrict__ W_in,
                                               const float* __restrict__ Ws,
                                               const float* __restrict__ W_out,
                                               __bf16* __restrict__ wfrag) {
  const int idx = blockIdx.x * 256 + threadIdx.x;
  if (idx >= 11264) return;
  int l, r, CT;
  if (idx < 10240) { l = idx >> 11; r = idx & 2047; CT = 8; }
  else             { l = 5; r = idx - 10240; CT = 4; }
  const int lane = r & 63;
  const int rr = r >> 6;
  const int ct = rr % CT;
  const int kc_i = rr / CT;
  const int lr = lane & 15, kg = lane >> 4;
  const int col = ct * 16 + lr;
  const int k0 = kc_i * 32 + kg * 8;
  const float* Wsrc;
  int ncols;
  if (l == 0)      { Wsrc = W_in; ncols = 128; }
  else if (l <= 4) { Wsrc = Ws + (size_t)(l - 1) * 16384; ncols = 128; }
  else             { Wsrc = W_out; ncols = 64; }
  bf16x8 hi, lo;
#pragma unroll
  for (int j = 0; j < 8; ++j) {
    float v = Wsrc[(size_t)(k0 + j) * ncols + col];
    __bf16 h = (__bf16)v;
    hi[j] = h;
    lo[j] = (__bf16)(v - (float)h);
  }
  const size_t lbase = (l < 5) ? (size_t)l * 65536 : (size_t)327680;
  char* outp = (char*)wfrag + lbase;
  *(bf16x8*)(outp + ((size_t)(kc_i * 2 + 0) * CT + ct) * 1024 + lane * 16) = hi;
  *(bf16x8*)(outp + ((size_t)(kc_i * 2 + 1) * CT + ct) * 1024 + lane * 16) = lo;
}

// ---------- MFMA GEMM: out = A[N,128] @ W  (A bf16 via LDS; B direct from L2) ----------
// BM=128 rows/block, 256 threads = 4 waves; wave wv owns rows wv*32..wv*32+31.
// A staged in LDS (XOR swizzle), ONE barrier; B fragments read fragment-ordered
// from global (L2-hot), no W LDS, no per-chunk barriers. LDS 32KB -> 4 blk/CU.
// Non-FINAL: writes t' = dis[row] * (A@W) as bf16 (pre-scaled for GCN norm).
// FINAL: writes fp32 out + bias.
template <int BNC, bool A_FP32, bool FINAL>
__global__ __launch_bounds__(256, 4) void k_mgemm(
    const void* __restrict__ in_v, const __bf16* __restrict__ wfrag,
    const float* __restrict__ dis, const float* __restrict__ out_bias,
    float* __restrict__ outf, __bf16* __restrict__ outh, int N) {
  constexpr int CT = BNC / 16;
  __shared__ __align__(16) char Abase[32768];  // [128 rows][128 k] bf16, swizzled

  const int tid = threadIdx.x;
  const int lane = tid & 63;
  const int wv = tid >> 6;
  const int lr = lane & 15;
  const int kg = lane >> 4;
  const int rowBase = blockIdx.x * 128;

  // ---- stage A ----
  if constexpr (A_FP32) {
    const float* in = (const float*)in_v;
    const int kq = tid & 31;  // float4 slot within row
#pragma unroll
    for (int i = 0; i < 16; ++i) {
      const int row = (tid >> 5) + i * 8;
      const int grow = rowBase + row;
      float4 v = make_float4(0.f, 0.f, 0.f, 0.f);
      if (grow < N) v = *(const float4*)(in + (size_t)grow * 128 + kq * 4);
      bf16x4 h;
      h[0] = (__bf16)v.x; h[1] = (__bf16)v.y; h[2] = (__bf16)v.z; h[3] = (__bf16)v.w;
      int byte = row * 256 + kq * 8;
      byte ^= (row & 7) << 4;
      *(bf16x4*)(Abase + byte) = h;
    }
  } else {
    const __bf16* in = (const __bf16*)in_v;
    const int kq = tid & 15;  // 16B slot within row
#pragma unroll
    for (int i = 0; i < 8; ++i) {
      const int row = (tid >> 4) + i * 16;
      const int grow = rowBase + row;
      uint4 v = make_uint4(0, 0, 0, 0);
      if (grow < N) v = *(const uint4*)(in + (size_t)grow * 128 + kq * 8);
      int byte = row * 256 + kq * 16;
      byte ^= (row & 7) << 4;
      *(uint4*)(Abase + byte) = v;
    }
  }
  __syncthreads();

  f32x4 acc[2][CT] = {};

#pragma unroll
  for (int kc_i = 0; kc_i < 4; ++kc_i) {
    bf16x8 afr[2];
#pragma unroll
    for (int rt = 0; rt < 2; ++rt) {
      const int row = wv * 32 + rt * 16 + lr;
      int byte = row * 256 + kc_i * 64 + kg * 16;
      byte ^= (row & 7) << 4;
      afr[rt] = *(const bf16x8*)(Abase + byte);
    }
    const char* wk = (const char*)wfrag + (size_t)kc_i * (2 * CT * 1024) +
                     (size_t)lane * 16;
#pragma unroll
    for (int ct = 0; ct < CT; ++ct) {
      bf16x8 bhi = *(const bf16x8*)(wk + ct * 1024);
      bf16x8 blo = *(const bf16x8*)(wk + (CT + ct) * 1024);
#pragma unroll
      for (int rt = 0; rt < 2; ++rt) {
        acc[rt][ct] = __builtin_amdgcn_mfma_f32_16x16x32_bf16(afr[rt], bhi,
                                                              acc[rt][ct], 0, 0, 0);
        acc[rt][ct] = __builtin_amdgcn_mfma_f32_16x16x32_bf16(afr[rt], blo,
                                                              acc[rt][ct], 0, 0, 0);
      }
    }
  }

  // ---- epilogue: C/D layout col=lane&15, row=(lane>>4)*4+j ----
  float ob[CT];
  if constexpr (FINAL) {
#pragma unroll
    for (int ct = 0; ct < CT; ++ct) ob[ct] = out_bias[ct * 16 + lr];
  }
#pragma unroll
  for (int rt = 0; rt < 2; ++rt) {
#pragma unroll
    for (int j = 0; j < 4; ++j) {
      const int row = rowBase + wv * 32 + rt * 16 + kg * 4 + j;
      if (row < N) {
        if constexpr (FINAL) {
#pragma unroll
          for (int ct = 0; ct < CT; ++ct)
            outf[(size_t)row * BNC + ct * 16 + lr] = acc[rt][ct][j] + ob[ct];
        } else {
          const float dr = dis[row];
#pragma unroll
          for (int ct = 0; ct < CT; ++ct)
            outh[(size_t)row * BNC + ct * 16 + lr] = (__bf16)(acc[rt][ct][j] * dr);
        }
      }
    }
  }
}

// ---------- CSR gather + BN + ReLU, burst-issue, coef-free:
// h[d] = relu(scale*(dis_d*(sum_e t'[src_e] + t'[d]) + bias) + shift), bf16.
// t' rows pre-scaled by dis (mgemm epilogue); pad lanes gather zero row N.
__global__ __launch_bounds__(256) void k_agg(const int* __restrict__ rowstart,
                                             const int* __restrict__ counts,
                                             const int* __restrict__ esrc,
                                             const __bf16* __restrict__ t,
                                             const float* __restrict__ dis,
                                             const float* __restrict__ bias,
                                             const float* __restrict__ scale,
                                             const float* __restrict__ shift,
                                             __bf16* __restrict__ h, int N) {
  const int lane = threadIdx.x & 63;
  const int wv = threadIdx.x >> 6;
  const int node = blockIdx.x * 4 + wv;
  if (node >= N) return;
  const int beg = rowstart[node];
  const int cnt = counts[node];
  const float dn = dis[node];

  // self term (independent issue)
  bf16x2 sv = *reinterpret_cast<const bf16x2*>(t + (size_t)node * 128 + lane * 2);
  // lane-parallel edge sources; pad with zero row N
  int rec = (lane < cnt) ? esrc[beg + lane] : N;

  float ax = (float)sv[0];
  float ay = (float)sv[1];

  const int m = cnt < 64 ? cnt : 64;
  const int rounds = (m + 7) >> 3;
  for (int r = 0; r < rounds; ++r) {
    const int base = r * 8;
#pragma unroll
    for (int u = 0; u < 8; ++u) {
      const int s = __builtin_amdgcn_readlane(rec, base + u);
      const bf16x2 v =
          *reinterpret_cast<const bf16x2*>(t + (size_t)s * 128 + lane * 2);
      ax += (float)v[0];
      ay += (float)v[1];
    }
  }
  // rare overflow (degree > 64)
  for (int i = 64; i < cnt; ++i) {
    const int s0 = esrc[beg + i];
    const bf16x2 v0 =
        *reinterpret_cast<const bf16x2*>(t + (size_t)s0 * 128 + lane * 2);
    ax += (float)v0[0];
    ay += (float)v0[1];
  }

  ax = fmaf(ax, dn, bias[lane * 2 + 0]);
  ay = fmaf(ay, dn, bias[lane * 2 + 1]);
  ax = fmaxf(fmaf(ax, scale[lane * 2 + 0], shift[lane * 2 + 0]), 0.f);
  ay = fmaxf(fmaf(ay, scale[lane * 2 + 1], shift[lane * 2 + 1]), 0.f);
  bf16x2 o;
  o[0] = (__bf16)ax;
  o[1] = (__bf16)ay;
  *reinterpret_cast<bf16x2*>(h + (size_t)node * 128 + lane * 2) = o;
}

// ---------- launch ----------
extern "C" void kernel_launch(void* const* d_in, const int* in_sizes, int n_in,
                              void* d_out, int out_size, void* d_ws, size_t ws_size,
                              hipStream_t stream) {
  const float* x      = (const float*)d_in[0];
  const int*   ei     = (const int*)d_in[1];
  const float* W_in   = (const float*)d_in[2];
  const float* b_in   = (const float*)d_in[3];
  const float* Ws     = (const float*)d_in[4];
  const float* bs     = (const float*)d_in[5];
  const float* gammas = (const float*)d_in[6];
  const float* betas  = (const float*)d_in[7];
  const float* mean   = (const float*)d_in[8];
  const float* var    = (const float*)d_in[9];
  const float* W_out  = (const float*)d_in[10];
  const float* b_out  = (const float*)d_in[11];
  float* out = (float*)d_out;

  const int N = in_sizes[0] / 128;
  const int E = in_sizes[1] / 2;
  const int* src = ei;
  const int* dst = ei + E;

  char* ws = (char*)d_ws;
  size_t off = 0;
  auto alloc = [&](size_t bytes) {
    void* p = ws + off;
    off = (off + bytes + 255) & ~255ULL;
    return p;
  };
  int*    counts   = (int*)alloc((size_t)N * 4);
  int*    rowstart = (int*)alloc((size_t)N * 4);
  int*    bsum     = (int*)alloc(256 * 4);
  int*    boff     = (int*)alloc(256 * 4);
  float*  dis      = (float*)alloc((size_t)N * 4);
  float*  scale    = (float*)alloc(5 * 128 * 4);
  float*  shift    = (float*)alloc(5 * 128 * 4);
  __bf16* wfrag    = (__bf16*)alloc(360448);  // 5*64KB + 32KB fragment-ordered W
  int*    rank     = (int*)alloc((size_t)E * 4);
  int*    esrc     = (int*)alloc((size_t)E * 4);
  __bf16* t        = (__bf16*)alloc(((size_t)N + 1) * 128 * 2);  // +1 zero pad row
  __bf16* h        = (__bf16*)alloc((size_t)N * 128 * 2);
  (void)ws_size;

  const int nb = (N + 1023) / 1024;

  hipMemsetAsync(counts, 0, (size_t)N * 4, stream);
  k_count<<<(E + 255) / 256, 256, 0, stream>>>(dst, counts, rank, E);
  k_dis<<<(N + 255) / 256, 256, 0, stream>>>(counts, dis, N);
  k_scan1<<<nb, 256, 0, stream>>>(counts, rowstart, bsum, N);
  k_scan2<<<1, 256, 0, stream>>>(bsum, boff, nb);
  k_fix<<<(N + 255) / 256, 256, 0, stream>>>(rowstart, boff, N);
  k_scatter<<<(E + 255) / 256, 256, 0, stream>>>(src, dst, rowstart, rank, esrc, E);
  k_bnparam<<<(5 * 128 + 255) / 256, 256, 0, stream>>>(gammas, betas, mean, var,
                                                       scale, shift, 5 * 128);
  k_wprep<<<44, 256, 0, stream>>>(W_in, Ws, W_out, wfrag);
  k_zrow<<<1, 64, 0, stream>>>(t, N);

  const int gblocks = (N + 127) / 128;
  const int ablocks = (N + 3) / 4;

  // t0' = dis * (bf16(x) @ W_in)
  k_mgemm<128, true, false><<<gblocks, 256, 0, stream>>>(
      x, wfrag, dis, nullptr, nullptr, t, N);

  const float* biases[5] = {b_in, bs, bs + 128, bs + 256, bs + 384};
  for (int l = 0; l < 4; ++l) {
    k_agg<<<ablocks, 256, 0, stream>>>(rowstart, counts, esrc, t, dis, biases[l],
                                       scale + l * 128, shift + l * 128, h, N);
    k_mgemm<128, false, false><<<gblocks, 256, 0, stream>>>(
        h, wfrag + (size_t)(l + 1) * 32768, dis, nullptr, nullptr, t, N);
  }
  k_agg<<<ablocks, 256, 0, stream>>>(rowstart, counts, esrc, t, dis, biases[4],
                                     scale + 4 * 128, shift + 4 * 128, h, N);
  k_mgemm<64, false, true><<<gblocks, 256, 0, stream>>>(
      h, wfrag + 163840, nullptr, b_out, out, nullptr, N);
}

// Round 9
// 334.513 us; speedup vs baseline: 2.2196x; 1.0588x over previous
//
#include <hip/hip_runtime.h>
#include <cstdint>

#define BN_EPS 1e-5f

typedef __bf16 bf16x8 __attribute__((ext_vector_type(8)));
typedef __bf16 bf16x4 __attribute__((ext_vector_type(4)));
typedef __bf16 bf16x2 __attribute__((ext_vector_type(2)));
typedef float f32x4 __attribute__((ext_vector_type(4)));

// ---------- CSR build ----------

// count in-degree AND record each edge's rank within its dst list
__global__ __launch_bounds__(256) void k_count(const int* __restrict__ dstv,
                                               int* __restrict__ counts,
                                               int* __restrict__ rank, int E) {
  int e = blockIdx.x * 256 + threadIdx.x;
  if (e < E) rank[e] = atomicAdd(counts + dstv[e], 1);
}

__global__ __launch_bounds__(256) void k_dis(const int* __restrict__ counts,
                                             float* __restrict__ dis, int N) {
  int i = blockIdx.x * 256 + threadIdx.x;
  if (i < N) dis[i] = rsqrtf((float)counts[i] + 1.0f);
}

// per-block (1024 elems) exclusive scan; block total -> bsum
__global__ __launch_bounds__(256) void k_scan1(const int* __restrict__ counts,
                                               int* __restrict__ rowstart,
                                               int* __restrict__ bsum, int N) {
  __shared__ int wsum[4];
  const int tid = threadIdx.x, lane = tid & 63, wv = tid >> 6;
  const int base = blockIdx.x * 1024 + tid * 4;
  int c[4];
#pragma unroll
  for (int j = 0; j < 4; ++j) {
    int idx = base + j;
    c[j] = (idx < N) ? counts[idx] : 0;
  }
  int s = c[0] + c[1] + c[2] + c[3];
  int x = s;  // inclusive wave scan
  for (int d = 1; d < 64; d <<= 1) {
    int y = __shfl_up(x, d);
    if (lane >= d) x += y;
  }
  if (lane == 63) wsum[wv] = x;
  __syncthreads();
  int woff = 0;
  for (int w = 0; w < wv; ++w) woff += wsum[w];
  int r = woff + x - s;
#pragma unroll
  for (int j = 0; j < 4; ++j) {
    int idx = base + j;
    if (idx < N) rowstart[idx] = r;
    r += c[j];
  }
  if (tid == 255) bsum[blockIdx.x] = woff + x;
}

__global__ __launch_bounds__(256) void k_scan2(const int* __restrict__ bsum,
                                               int* __restrict__ boff, int nb) {
  __shared__ int sm[256];
  const int tid = threadIdx.x;
  int v = (tid < nb) ? bsum[tid] : 0;
  sm[tid] = v;
  __syncthreads();
  for (int d = 1; d < 256; d <<= 1) {
    int y = (tid >= d) ? sm[tid - d] : 0;
    __syncthreads();
    sm[tid] += y;
    __syncthreads();
  }
  if (tid < nb) boff[tid] = sm[tid] - v;
}

__global__ __launch_bounds__(256) void k_fix(int* __restrict__ rowstart,
                                             const int* __restrict__ boff, int N) {
  int i = blockIdx.x * 256 + threadIdx.x;
  if (i < N) rowstart[i] += boff[i >> 10];
}

// atomic-free placement: esrc[rowstart[dst] + rank] = src
__global__ __launch_bounds__(256) void k_scatter(const int* __restrict__ src,
                                                 const int* __restrict__ dstv,
                                                 const int* __restrict__ rowstart,
                                                 const int* __restrict__ rank,
                                                 int* __restrict__ esrc, int E) {
  int e = blockIdx.x * 256 + threadIdx.x;
  if (e < E) esrc[rowstart[dstv[e]] + rank[e]] = src[e];
}

__global__ __launch_bounds__(256) void k_bnparam(const float* __restrict__ gamma,
                                                 const float* __restrict__ beta,
                                                 const float* __restrict__ mean,
                                                 const float* __restrict__ var,
                                                 float* __restrict__ scale,
                                                 float* __restrict__ shift, int n) {
  int i = blockIdx.x * 256 + threadIdx.x;
  if (i < n) {
    float s = gamma[i] * rsqrtf(var[i] + BN_EPS);
    scale[i] = s;
    shift[i] = beta[i] - mean[i] * s;
  }
}

// zero pad row N of a t buffer (gather target for padded lanes)
__global__ __launch_bounds__(64) void k_zrow(__bf16* __restrict__ t, int N) {
  bf16x2 z;
  z[0] = (__bf16)0.f;
  z[1] = (__bf16)0.f;
  *reinterpret_cast<bf16x2*>(t + (size_t)N * 128 + threadIdx.x * 2) = z;
}

// ---------- weight prep: fp32 W -> bf16 hi/lo in MFMA FRAGMENT ORDER ----------
// Per layer, per kc_i(4) x plane(2) x ct(CT): a 1KB block of 64 lanes x 16B.
// Lane (lr=lane&15, kg=lane>>4) holds W[k0..k0+8)[ct*16+lr], k0=kc_i*32+kg*8.
// Layers 0..4: CT=8, 64KB each at l*65536 B. Final: CT=4, 32KB at 327680 B.
__global__ __launch_bounds__(256) void k_wprep(const float* __restrict__ W_in,
                                               const float* __restrict__ Ws,
                                               const float* __restrict__ W_out,
                                               __bf16* __restrict__ wfrag) {
  const int idx = blockIdx.x * 256 + threadIdx.x;
  if (idx >= 11264) return;
  int l, r, CT;
  if (idx < 10240) { l = idx >> 11; r = idx & 2047; CT = 8; }
  else             { l = 5; r = idx - 10240; CT = 4; }
  const int lane = r & 63;
  const int rr = r >> 6;
  const int ct = rr % CT;
  const int kc_i = rr / CT;
  const int lr = lane & 15, kg = lane >> 4;
  const int col = ct * 16 + lr;
  const int k0 = kc_i * 32 + kg * 8;
  const float* Wsrc;
  int ncols;
  if (l == 0)      { Wsrc = W_in; ncols = 128; }
  else if (l <= 4) { Wsrc = Ws + (size_t)(l - 1) * 16384; ncols = 128; }
  else             { Wsrc = W_out; ncols = 64; }
  bf16x8 hi, lo;
#pragma unroll
  for (int j = 0; j < 8; ++j) {
    float v = Wsrc[(size_t)(k0 + j) * ncols + col];
    __bf16 h = (__bf16)v;
    hi[j] = h;
    lo[j] = (__bf16)(v - (float)h);
  }
  const size_t lbase = (l < 5) ? (size_t)l * 65536 : (size_t)327680;
  char* outp = (char*)wfrag + lbase;
  *(bf16x8*)(outp + ((size_t)(kc_i * 2 + 0) * CT + ct) * 1024 + lane * 16) = hi;
  *(bf16x8*)(outp + ((size_t)(kc_i * 2 + 1) * CT + ct) * 1024 + lane * 16) = lo;
}

// ---------- MFMA GEMM for layer 0: t' = dis * (bf16(x) @ W_in) ----------
__global__ __launch_bounds__(256, 4) void k_mgemm0(
    const float* __restrict__ in, const __bf16* __restrict__ wfrag,
    const float* __restrict__ dis, __bf16* __restrict__ outh, int N) {
  constexpr int CT = 8;
  __shared__ __align__(16) char Abase[32768];  // [128 rows][128 k] bf16, swizzled

  const int tid = threadIdx.x;
  const int lane = tid & 63;
  const int wv = tid >> 6;
  const int lr = lane & 15;
  const int kg = lane >> 4;
  const int rowBase = blockIdx.x * 128;

  {
    const int kq = tid & 31;  // float4 slot within row
#pragma unroll
    for (int i = 0; i < 16; ++i) {
      const int row = (tid >> 5) + i * 8;
      const int grow = rowBase + row;
      float4 v = make_float4(0.f, 0.f, 0.f, 0.f);
      if (grow < N) v = *(const float4*)(in + (size_t)grow * 128 + kq * 4);
      bf16x4 h;
      h[0] = (__bf16)v.x; h[1] = (__bf16)v.y; h[2] = (__bf16)v.z; h[3] = (__bf16)v.w;
      int byte = row * 256 + kq * 8;
      byte ^= (row & 7) << 4;
      *(bf16x4*)(Abase + byte) = h;
    }
  }
  __syncthreads();

  f32x4 acc[2][CT] = {};
#pragma unroll
  for (int kc_i = 0; kc_i < 4; ++kc_i) {
    bf16x8 afr[2];
#pragma unroll
    for (int rt = 0; rt < 2; ++rt) {
      const int row = wv * 32 + rt * 16 + lr;
      int byte = row * 256 + kc_i * 64 + kg * 16;
      byte ^= (row & 7) << 4;
      afr[rt] = *(const bf16x8*)(Abase + byte);
    }
    const char* wk = (const char*)wfrag + (size_t)kc_i * (2 * CT * 1024) +
                     (size_t)lane * 16;
#pragma unroll
    for (int ct = 0; ct < CT; ++ct) {
      bf16x8 bhi = *(const bf16x8*)(wk + ct * 1024);
      bf16x8 blo = *(const bf16x8*)(wk + (CT + ct) * 1024);
#pragma unroll
      for (int rt = 0; rt < 2; ++rt) {
        acc[rt][ct] = __builtin_amdgcn_mfma_f32_16x16x32_bf16(afr[rt], bhi,
                                                              acc[rt][ct], 0, 0, 0);
        acc[rt][ct] = __builtin_amdgcn_mfma_f32_16x16x32_bf16(afr[rt], blo,
                                                              acc[rt][ct], 0, 0, 0);
      }
    }
  }

#pragma unroll
  for (int rt = 0; rt < 2; ++rt) {
#pragma unroll
    for (int j = 0; j < 4; ++j) {
      const int row = rowBase + wv * 32 + rt * 16 + kg * 4 + j;
      if (row < N) {
        const float dr = dis[row];
#pragma unroll
        for (int ct = 0; ct < CT; ++ct)
          outh[(size_t)row * 128 + ct * 16 + lr] = (__bf16)(acc[rt][ct][j] * dr);
      }
    }
  }
}

// ---------- FUSED layer: [gather agg + BN + ReLU -> LDS] -> MFMA GEMM ----------
// Per block: 128 nodes; wave wv gathers its own 32 MFMA rows (burst-issue,
// record prefetch pipelined across nodes), writes bf16 h rows to LDS (4B/lane,
// conflict-free), ONE barrier, then the proven MFMA loop (W fragments from L2).
// Non-FINAL: t_out' = dis[row]*(h@W) bf16. FINAL: out = h@W_out + bias, fp32.
template <int CT, bool FINAL>
__global__ __launch_bounds__(256, 4) void k_layer(
    const __bf16* __restrict__ tin, const __bf16* __restrict__ wfrag,
    const int* __restrict__ rowstart, const int* __restrict__ counts,
    const int* __restrict__ esrc, const float* __restrict__ dis,
    const float* __restrict__ bias, const float* __restrict__ scale,
    const float* __restrict__ shift, const float* __restrict__ out_bias,
    float* __restrict__ outf, __bf16* __restrict__ outh, int N) {
  __shared__ __align__(16) char Abase[32768];  // [128 rows][128 k] bf16, swizzled

  const int tid = threadIdx.x;
  const int lane = tid & 63;
  const int wv = tid >> 6;
  const int lr = lane & 15;
  const int kg = lane >> 4;
  const int rowBase = blockIdx.x * 128;

  // ---- phase 1: gather + BN + ReLU for this wave's 32 rows ----
  {
    const int nb0 = rowBase + wv * 32;
    // lane-parallel metadata for the 32 nodes (lane<32)
    int mb = 0, mc = 0, mdbits = 0;
    if (lane < 32) {
      const int nd = nb0 + lane;
      if (nd < N) {
        mb = rowstart[nd];
        mc = counts[nd];
        mdbits = __float_as_int(dis[nd]);
      }
    }
    const int f0 = lane * 2;
    const float bx = bias[f0], by = bias[f0 + 1];
    const float scx = scale[f0], scy = scale[f0 + 1];
    const float shx = shift[f0], shy = shift[f0 + 1];

    // prefetch node 0's edge records
    int ci = __builtin_amdgcn_readlane(mc, 0);
    int rec = (lane < ci) ? esrc[__builtin_amdgcn_readlane(mb, 0) + lane] : N;

    for (int i = 0; i < 32; ++i) {
      const int node = nb0 + i;
      const float dn = __int_as_float(__builtin_amdgcn_readlane(mdbits, i));
      const int srow = (node < N) ? node : N;
      const bf16x2 sv =
          *reinterpret_cast<const bf16x2*>(tin + (size_t)srow * 128 + f0);
      // prefetch next node's records (overlaps with this node's gathers)
      int rec_n = N, cn = 0;
      if (i < 31) {
        const int bn_ = __builtin_amdgcn_readlane(mb, i + 1);
        cn = __builtin_amdgcn_readlane(mc, i + 1);
        if (lane < cn) rec_n = esrc[bn_ + lane];
      }
      float ax = (float)sv[0];
      float ay = (float)sv[1];
      const int m = ci < 64 ? ci : 64;
      const int rounds = (m + 7) >> 3;
      for (int r = 0; r < rounds; ++r) {
        const int rb = r * 8;
#pragma unroll
        for (int u = 0; u < 8; ++u) {
          const int s = __builtin_amdgcn_readlane(rec, rb + u);
          const bf16x2 v =
              *reinterpret_cast<const bf16x2*>(tin + (size_t)s * 128 + f0);
          ax += (float)v[0];
          ay += (float)v[1];
        }
      }
      if (__builtin_expect(ci > 64, 0)) {  // rare high-degree tail
        const int bi = __builtin_amdgcn_readlane(mb, i);
        for (int e = 64; e < ci; ++e) {
          const int s0 = esrc[bi + e];
          const bf16x2 v0 =
              *reinterpret_cast<const bf16x2*>(tin + (size_t)s0 * 128 + f0);
          ax += (float)v0[0];
          ay += (float)v0[1];
        }
      }
      ax = fmaf(ax, dn, bx);
      ay = fmaf(ay, dn, by);
      ax = fmaxf(fmaf(ax, scx, shx), 0.f);
      ay = fmaxf(fmaf(ay, scy, shy), 0.f);
      bf16x2 o;
      o[0] = (__bf16)ax;
      o[1] = (__bf16)ay;
      const int row = wv * 32 + i;
      int byte = row * 256 + lane * 4;
      byte ^= (row & 7) << 4;
      *(bf16x2*)(Abase + byte) = o;
      rec = rec_n;
      ci = cn;
    }
  }
  __syncthreads();

  // ---- phase 2: MFMA (A from LDS, W fragments direct from L2) ----
  f32x4 acc[2][CT] = {};
#pragma unroll
  for (int kc_i = 0; kc_i < 4; ++kc_i) {
    bf16x8 afr[2];
#pragma unroll
    for (int rt = 0; rt < 2; ++rt) {
      const int row = wv * 32 + rt * 16 + lr;
      int byte = row * 256 + kc_i * 64 + kg * 16;
      byte ^= (row & 7) << 4;
      afr[rt] = *(const bf16x8*)(Abase + byte);
    }
    const char* wk = (const char*)wfrag + (size_t)kc_i * (2 * CT * 1024) +
                     (size_t)lane * 16;
#pragma unroll
    for (int ct = 0; ct < CT; ++ct) {
      bf16x8 bhi = *(const bf16x8*)(wk + ct * 1024);
      bf16x8 blo = *(const bf16x8*)(wk + (CT + ct) * 1024);
#pragma unroll
      for (int rt = 0; rt < 2; ++rt) {
        acc[rt][ct] = __builtin_amdgcn_mfma_f32_16x16x32_bf16(afr[rt], bhi,
                                                              acc[rt][ct], 0, 0, 0);
        acc[rt][ct] = __builtin_amdgcn_mfma_f32_16x16x32_bf16(afr[rt], blo,
                                                              acc[rt][ct], 0, 0, 0);
      }
    }
  }

  // ---- epilogue: C/D layout col=lane&15, row=(lane>>4)*4+j ----
  float ob[CT];
  if constexpr (FINAL) {
#pragma unroll
    for (int ct = 0; ct < CT; ++ct) ob[ct] = out_bias[ct * 16 + lr];
  }
#pragma unroll
  for (int rt = 0; rt < 2; ++rt) {
#pragma unroll
    for (int j = 0; j < 4; ++j) {
      const int row = rowBase + wv * 32 + rt * 16 + kg * 4 + j;
      if (row < N) {
        if constexpr (FINAL) {
#pragma unroll
          for (int ct = 0; ct < CT; ++ct)
            outf[(size_t)row * (CT * 16) + ct * 16 + lr] = acc[rt][ct][j] + ob[ct];
        } else {
          const float dr = dis[row];
#pragma unroll
          for (int ct = 0; ct < CT; ++ct)
            outh[(size_t)row * 128 + ct * 16 + lr] = (__bf16)(acc[rt][ct][j] * dr);
        }
      }
    }
  }
}

// ---------- launch ----------
extern "C" void kernel_launch(void* const* d_in, const int* in_sizes, int n_in,
                              void* d_out, int out_size, void* d_ws, size_t ws_size,
                              hipStream_t stream) {
  const float* x      = (const float*)d_in[0];
  const int*   ei     = (const int*)d_in[1];
  const float* W_in   = (const float*)d_in[2];
  const float* b_in   = (const float*)d_in[3];
  const float* Ws     = (const float*)d_in[4];
  const float* bs     = (const float*)d_in[5];
  const float* gammas = (const float*)d_in[6];
  const float* betas  = (const float*)d_in[7];
  const float* mean   = (const float*)d_in[8];
  const float* var    = (const float*)d_in[9];
  const float* W_out  = (const float*)d_in[10];
  const float* b_out  = (const float*)d_in[11];
  float* out = (float*)d_out;

  const int N = in_sizes[0] / 128;
  const int E = in_sizes[1] / 2;
  const int* src = ei;
  const int* dst = ei + E;

  char* ws = (char*)d_ws;
  size_t off = 0;
  auto alloc = [&](size_t bytes) {
    void* p = ws + off;
    off = (off + bytes + 255) & ~255ULL;
    return p;
  };
  int*    counts   = (int*)alloc((size_t)N * 4);
  int*    rowstart = (int*)alloc((size_t)N * 4);
  int*    bsum     = (int*)alloc(256 * 4);
  int*    boff     = (int*)alloc(256 * 4);
  float*  dis      = (float*)alloc((size_t)N * 4);
  float*  scale    = (float*)alloc(5 * 128 * 4);
  float*  shift    = (float*)alloc(5 * 128 * 4);
  __bf16* wfrag    = (__bf16*)alloc(360448);  // 5*64KB + 32KB fragment-ordered W
  int*    rank     = (int*)alloc((size_t)E * 4);
  int*    esrc     = (int*)alloc((size_t)E * 4);
  __bf16* tA       = (__bf16*)alloc(((size_t)N + 1) * 128 * 2);  // +1 zero pad row
  __bf16* tB       = (__bf16*)alloc(((size_t)N + 1) * 128 * 2);
  (void)ws_size;

  const int nb = (N + 1023) / 1024;

  hipMemsetAsync(counts, 0, (size_t)N * 4, stream);
  k_count<<<(E + 255) / 256, 256, 0, stream>>>(dst, counts, rank, E);
  k_dis<<<(N + 255) / 256, 256, 0, stream>>>(counts, dis, N);
  k_scan1<<<nb, 256, 0, stream>>>(counts, rowstart, bsum, N);
  k_scan2<<<1, 256, 0, stream>>>(bsum, boff, nb);
  k_fix<<<(N + 255) / 256, 256, 0, stream>>>(rowstart, boff, N);
  k_scatter<<<(E + 255) / 256, 256, 0, stream>>>(src, dst, rowstart, rank, esrc, E);
  k_bnparam<<<(5 * 128 + 255) / 256, 256, 0, stream>>>(gammas, betas, mean, var,
                                                       scale, shift, 5 * 128);
  k_wprep<<<44, 256, 0, stream>>>(W_in, Ws, W_out, wfrag);
  k_zrow<<<1, 64, 0, stream>>>(tA, N);
  k_zrow<<<1, 64, 0, stream>>>(tB, N);

  const int gblocks = (N + 127) / 128;

  // t0' = dis * (bf16(x) @ W_in)  -> tA
  k_mgemm0<<<gblocks, 256, 0, stream>>>(x, wfrag, dis, tA, N);

  const float* biases[5] = {b_in, bs, bs + 128, bs + 256, bs + 384};
  __bf16* tin = tA;
  __bf16* tout = tB;
  for (int l = 1; l <= 4; ++l) {
    k_layer<8, false><<<gblocks, 256, 0, stream>>>(
        tin, wfrag + (size_t)l * 32768, rowstart, counts, esrc, dis,
        biases[l - 1], scale + (l - 1) * 128, shift + (l - 1) * 128, nullptr,
        nullptr, tout, N);
    __bf16* tmp = tin;
    tin = tout;
    tout = tmp;
  }
  k_layer<4, true><<<gblocks, 256, 0, stream>>>(
      tin, wfrag + 163840, rowstart, counts, esrc, dis, biases[4],
      scale + 4 * 128, shift + 4 * 128, b_out, out, nullptr, N);
}

// Round 10
// 293.404 us; speedup vs baseline: 2.5306x; 1.1401x over previous
//
#include <hip/hip_runtime.h>
#include <cstdint>

#define BN_EPS 1e-5f

typedef __bf16 bf16x8 __attribute__((ext_vector_type(8)));
typedef __bf16 bf16x4 __attribute__((ext_vector_type(4)));
typedef __bf16 bf16x2 __attribute__((ext_vector_type(2)));
typedef float f32x4 __attribute__((ext_vector_type(4)));

// ---------- CSR build ----------

// count in-degree AND record each edge's rank within its dst list
__global__ __launch_bounds__(256) void k_count(const int* __restrict__ dstv,
                                               int* __restrict__ counts,
                                               int* __restrict__ rank, int E) {
  int e = blockIdx.x * 256 + threadIdx.x;
  if (e < E) rank[e] = atomicAdd(counts + dstv[e], 1);
}

__global__ __launch_bounds__(256) void k_dis(const int* __restrict__ counts,
                                             float* __restrict__ dis, int N) {
  int i = blockIdx.x * 256 + threadIdx.x;
  if (i < N) dis[i] = rsqrtf((float)counts[i] + 1.0f);
}

// per-block (1024 elems) exclusive scan; block total -> bsum
__global__ __launch_bounds__(256) void k_scan1(const int* __restrict__ counts,
                                               int* __restrict__ rowstart,
                                               int* __restrict__ bsum, int N) {
  __shared__ int wsum[4];
  const int tid = threadIdx.x, lane = tid & 63, wv = tid >> 6;
  const int base = blockIdx.x * 1024 + tid * 4;
  int c[4];
#pragma unroll
  for (int j = 0; j < 4; ++j) {
    int idx = base + j;
    c[j] = (idx < N) ? counts[idx] : 0;
  }
  int s = c[0] + c[1] + c[2] + c[3];
  int x = s;  // inclusive wave scan
  for (int d = 1; d < 64; d <<= 1) {
    int y = __shfl_up(x, d);
    if (lane >= d) x += y;
  }
  if (lane == 63) wsum[wv] = x;
  __syncthreads();
  int woff = 0;
  for (int w = 0; w < wv; ++w) woff += wsum[w];
  int r = woff + x - s;
#pragma unroll
  for (int j = 0; j < 4; ++j) {
    int idx = base + j;
    if (idx < N) rowstart[idx] = r;
    r += c[j];
  }
  if (tid == 255) bsum[blockIdx.x] = woff + x;
}

__global__ __launch_bounds__(256) void k_scan2(const int* __restrict__ bsum,
                                               int* __restrict__ boff, int nb) {
  __shared__ int sm[256];
  const int tid = threadIdx.x;
  int v = (tid < nb) ? bsum[tid] : 0;
  sm[tid] = v;
  __syncthreads();
  for (int d = 1; d < 256; d <<= 1) {
    int y = (tid >= d) ? sm[tid - d] : 0;
    __syncthreads();
    sm[tid] += y;
    __syncthreads();
  }
  if (tid < nb) boff[tid] = sm[tid] - v;
}

__global__ __launch_bounds__(256) void k_fix(int* __restrict__ rowstart,
                                             const int* __restrict__ boff, int N) {
  int i = blockIdx.x * 256 + threadIdx.x;
  if (i < N) rowstart[i] += boff[i >> 10];
}

// atomic-free placement: esrc[rowstart[dst] + rank] = src
__global__ __launch_bounds__(256) void k_scatter(const int* __restrict__ src,
                                                 const int* __restrict__ dstv,
                                                 const int* __restrict__ rowstart,
                                                 const int* __restrict__ rank,
                                                 int* __restrict__ esrc, int E) {
  int e = blockIdx.x * 256 + threadIdx.x;
  if (e < E) esrc[rowstart[dstv[e]] + rank[e]] = src[e];
}

__global__ __launch_bounds__(256) void k_bnparam(const float* __restrict__ gamma,
                                                 const float* __restrict__ beta,
                                                 const float* __restrict__ mean,
                                                 const float* __restrict__ var,
                                                 float* __restrict__ scale,
                                                 float* __restrict__ shift, int n) {
  int i = blockIdx.x * 256 + threadIdx.x;
  if (i < n) {
    float s = gamma[i] * rsqrtf(var[i] + BN_EPS);
    scale[i] = s;
    shift[i] = beta[i] - mean[i] * s;
  }
}

// zero pad row N of a t buffer (gather target for padded lanes)
__global__ __launch_bounds__(64) void k_zrow(__bf16* __restrict__ t, int N) {
  bf16x2 z;
  z[0] = (__bf16)0.f;
  z[1] = (__bf16)0.f;
  *reinterpret_cast<bf16x2*>(t + (size_t)N * 128 + threadIdx.x * 2) = z;
}

// ---------- weight prep: fp32 W -> bf16 hi/lo in MFMA FRAGMENT ORDER ----------
// Per layer, per kc_i(4) x plane(2) x ct(CT): a 1KB block of 64 lanes x 16B.
// Lane (lr=lane&15, kg=lane>>4) holds W[k0..k0+8)[ct*16+lr], k0=kc_i*32+kg*8.
// Layers 0..4: CT=8, 64KB each at l*65536 B. Final: CT=4, 32KB at 327680 B.
__global__ __launch_bounds__(256) void k_wprep(const float* __restrict__ W_in,
                                               const float* __restrict__ Ws,
                                               const float* __restrict__ W_out,
                                               __bf16* __restrict__ wfrag) {
  const int idx = blockIdx.x * 256 + threadIdx.x;
  if (idx >= 11264) return;
  int l, r, CT;
  if (idx < 10240) { l = idx >> 11; r = idx & 2047; CT = 8; }
  else             { l = 5; r = idx - 10240; CT = 4; }
  const int lane = r & 63;
  const int rr = r >> 6;
  const int ct = rr % CT;
  const int kc_i = rr / CT;
  const int lr = lane & 15, kg = lane >> 4;
  const int col = ct * 16 + lr;
  const int k0 = kc_i * 32 + kg * 8;
  const float* Wsrc;
  int ncols;
  if (l == 0)      { Wsrc = W_in; ncols = 128; }
  else if (l <= 4) { Wsrc = Ws + (size_t)(l - 1) * 16384; ncols = 128; }
  else             { Wsrc = W_out; ncols = 64; }
  bf16x8 hi, lo;
#pragma unroll
  for (int j = 0; j < 8; ++j) {
    float v = Wsrc[(size_t)(k0 + j) * ncols + col];
    __bf16 h = (__bf16)v;
    hi[j] = h;
    lo[j] = (__bf16)(v - (float)h);
  }
  const size_t lbase = (l < 5) ? (size_t)l * 65536 : (size_t)327680;
  char* outp = (char*)wfrag + lbase;
  *(bf16x8*)(outp + ((size_t)(kc_i * 2 + 0) * CT + ct) * 1024 + lane * 16) = hi;
  *(bf16x8*)(outp + ((size_t)(kc_i * 2 + 1) * CT + ct) * 1024 + lane * 16) = lo;
}

// ---------- MFMA GEMM for layer 0: t' = dis * (bf16(x) @ W_in) ----------
__global__ __launch_bounds__(256, 4) void k_mgemm0(
    const float* __restrict__ in, const __bf16* __restrict__ wfrag,
    const float* __restrict__ dis, __bf16* __restrict__ outh, int N) {
  constexpr int CT = 8;
  __shared__ __align__(16) char Abase[32768];  // [128 rows][128 k] bf16, swizzled

  const int tid = threadIdx.x;
  const int lane = tid & 63;
  const int wv = tid >> 6;
  const int lr = lane & 15;
  const int kg = lane >> 4;
  const int rowBase = blockIdx.x * 128;

  {
    const int kq = tid & 31;  // float4 slot within row
#pragma unroll
    for (int i = 0; i < 16; ++i) {
      const int row = (tid >> 5) + i * 8;
      const int grow = rowBase + row;
      float4 v = make_float4(0.f, 0.f, 0.f, 0.f);
      if (grow < N) v = *(const float4*)(in + (size_t)grow * 128 + kq * 4);
      bf16x4 h;
      h[0] = (__bf16)v.x; h[1] = (__bf16)v.y; h[2] = (__bf16)v.z; h[3] = (__bf16)v.w;
      int byte = row * 256 + kq * 8;
      byte ^= (row & 7) << 4;
      *(bf16x4*)(Abase + byte) = h;
    }
  }
  __syncthreads();

  f32x4 acc[2][CT] = {};
#pragma unroll
  for (int kc_i = 0; kc_i < 4; ++kc_i) {
    bf16x8 afr[2];
#pragma unroll
    for (int rt = 0; rt < 2; ++rt) {
      const int row = wv * 32 + rt * 16 + lr;
      int byte = row * 256 + kc_i * 64 + kg * 16;
      byte ^= (row & 7) << 4;
      afr[rt] = *(const bf16x8*)(Abase + byte);
    }
    const char* wk = (const char*)wfrag + (size_t)kc_i * (2 * CT * 1024) +
                     (size_t)lane * 16;
#pragma unroll
    for (int ct = 0; ct < CT; ++ct) {
      bf16x8 bhi = *(const bf16x8*)(wk + ct * 1024);
      bf16x8 blo = *(const bf16x8*)(wk + (CT + ct) * 1024);
#pragma unroll
      for (int rt = 0; rt < 2; ++rt) {
        acc[rt][ct] = __builtin_amdgcn_mfma_f32_16x16x32_bf16(afr[rt], bhi,
                                                              acc[rt][ct], 0, 0, 0);
        acc[rt][ct] = __builtin_amdgcn_mfma_f32_16x16x32_bf16(afr[rt], blo,
                                                              acc[rt][ct], 0, 0, 0);
      }
    }
  }

#pragma unroll
  for (int rt = 0; rt < 2; ++rt) {
#pragma unroll
    for (int j = 0; j < 4; ++j) {
      const int row = rowBase + wv * 32 + rt * 16 + kg * 4 + j;
      if (row < N) {
        const float dr = dis[row];
#pragma unroll
        for (int ct = 0; ct < CT; ++ct)
          outh[(size_t)row * 128 + ct * 16 + lr] = (__bf16)(acc[rt][ct][j] * dr);
      }
    }
  }
}

// ---------- FUSED layer: [gather agg + BN + ReLU -> LDS] -> MFMA GEMM ----------
// BM=64, 4 waves; wave wv owns rows wv*16..wv*16+15 — gathers them AND computes
// their MFMA rowtile. No cross-wave LDS sharing -> NO __syncthreads(); waves
// free-run so one wave's MFMA overlaps another's gather. 16KB LDS +
// __launch_bounds__(256,6) -> 6 blocks/CU (24 waves) for gather TLP.
// Non-FINAL: t_out' = dis[row]*(h@W) bf16. FINAL: out = h@W_out + bias, fp32.
template <int CT, bool FINAL>
__global__ __launch_bounds__(256, 6) void k_layer(
    const __bf16* __restrict__ tin, const __bf16* __restrict__ wfrag,
    const int* __restrict__ rowstart, const int* __restrict__ counts,
    const int* __restrict__ esrc, const float* __restrict__ dis,
    const float* __restrict__ bias, const float* __restrict__ scale,
    const float* __restrict__ shift, const float* __restrict__ out_bias,
    float* __restrict__ outf, __bf16* __restrict__ outh, int N) {
  __shared__ __align__(16) char Abase[16384];  // [64 rows][128 k] bf16, swizzled

  const int tid = threadIdx.x;
  const int lane = tid & 63;
  const int wv = tid >> 6;
  const int lr = lane & 15;
  const int kg = lane >> 4;
  const int rowBase = blockIdx.x * 64;

  // ---- phase 1: gather + BN + ReLU for this wave's 16 rows ----
  {
    const int nb0 = rowBase + wv * 16;
    // lane-parallel metadata for the 16 nodes (lane<16)
    int mb = 0, mc = 0, mdbits = 0;
    if (lane < 16) {
      const int nd = nb0 + lane;
      if (nd < N) {
        mb = rowstart[nd];
        mc = counts[nd];
        mdbits = __float_as_int(dis[nd]);
      }
    }
    const int f0 = lane * 2;
    const float bx = bias[f0], by = bias[f0 + 1];
    const float scx = scale[f0], scy = scale[f0 + 1];
    const float shx = shift[f0], shy = shift[f0 + 1];

    // prefetch node 0's edge records
    int ci = __builtin_amdgcn_readlane(mc, 0);
    int rec = (lane < ci) ? esrc[__builtin_amdgcn_readlane(mb, 0) + lane] : N;

    for (int i = 0; i < 16; ++i) {
      const int node = nb0 + i;
      const float dn = __int_as_float(__builtin_amdgcn_readlane(mdbits, i));
      const int srow = (node < N) ? node : N;
      const bf16x2 sv =
          *reinterpret_cast<const bf16x2*>(tin + (size_t)srow * 128 + f0);
      // prefetch next node's records (overlaps with this node's gathers)
      int rec_n = N, cn = 0;
      if (i < 15) {
        const int bn_ = __builtin_amdgcn_readlane(mb, i + 1);
        cn = __builtin_amdgcn_readlane(mc, i + 1);
        if (lane < cn) rec_n = esrc[bn_ + lane];
      }
      float ax = (float)sv[0];
      float ay = (float)sv[1];
      const int m = ci < 64 ? ci : 64;
      const int rounds = (m + 7) >> 3;
      for (int r = 0; r < rounds; ++r) {
        const int rb = r * 8;
#pragma unroll
        for (int u = 0; u < 8; ++u) {
          const int s = __builtin_amdgcn_readlane(rec, rb + u);
          const bf16x2 v =
              *reinterpret_cast<const bf16x2*>(tin + (size_t)s * 128 + f0);
          ax += (float)v[0];
          ay += (float)v[1];
        }
      }
      if (__builtin_expect(ci > 64, 0)) {  // rare high-degree tail
        const int bi = __builtin_amdgcn_readlane(mb, i);
        for (int e = 64; e < ci; ++e) {
          const int s0 = esrc[bi + e];
          const bf16x2 v0 =
              *reinterpret_cast<const bf16x2*>(tin + (size_t)s0 * 128 + f0);
          ax += (float)v0[0];
          ay += (float)v0[1];
        }
      }
      ax = fmaf(ax, dn, bx);
      ay = fmaf(ay, dn, by);
      ax = fmaxf(fmaf(ax, scx, shx), 0.f);
      ay = fmaxf(fmaf(ay, scy, shy), 0.f);
      bf16x2 o;
      o[0] = (__bf16)ax;
      o[1] = (__bf16)ay;
      const int row = wv * 16 + i;
      int byte = row * 256 + lane * 4;
      byte ^= (row & 7) << 4;
      *(bf16x2*)(Abase + byte) = o;
      rec = rec_n;
      ci = cn;
    }
  }
  // same-wave LDS RAW only (wave reads just its own 16 rows) — no barrier
  __threadfence_block();

  // ---- phase 2: MFMA (A from LDS, W fragments direct from L2) ----
  f32x4 acc[CT] = {};
#pragma unroll
  for (int kc_i = 0; kc_i < 4; ++kc_i) {
    const int row = wv * 16 + lr;
    int byte = row * 256 + kc_i * 64 + kg * 16;
    byte ^= (row & 7) << 4;
    const bf16x8 afr = *(const bf16x8*)(Abase + byte);
    const char* wk = (const char*)wfrag + (size_t)kc_i * (2 * CT * 1024) +
                     (size_t)lane * 16;
#pragma unroll
    for (int ct = 0; ct < CT; ++ct) {
      bf16x8 bhi = *(const bf16x8*)(wk + ct * 1024);
      bf16x8 blo = *(const bf16x8*)(wk + (CT + ct) * 1024);
      acc[ct] = __builtin_amdgcn_mfma_f32_16x16x32_bf16(afr, bhi, acc[ct], 0, 0, 0);
      acc[ct] = __builtin_amdgcn_mfma_f32_16x16x32_bf16(afr, blo, acc[ct], 0, 0, 0);
    }
  }

  // ---- epilogue: C/D layout col=lane&15, row=(lane>>4)*4+j ----
  float ob[CT];
  if constexpr (FINAL) {
#pragma unroll
    for (int ct = 0; ct < CT; ++ct) ob[ct] = out_bias[ct * 16 + lr];
  }
#pragma unroll
  for (int j = 0; j < 4; ++j) {
    const int row = rowBase + wv * 16 + kg * 4 + j;
    if (row < N) {
      if constexpr (FINAL) {
#pragma unroll
        for (int ct = 0; ct < CT; ++ct)
          outf[(size_t)row * (CT * 16) + ct * 16 + lr] = acc[ct][j] + ob[ct];
      } else {
        const float dr = dis[row];
#pragma unroll
        for (int ct = 0; ct < CT; ++ct)
          outh[(size_t)row * 128 + ct * 16 + lr] = (__bf16)(acc[ct][j] * dr);
      }
    }
  }
}

// ---------- launch ----------
extern "C" void kernel_launch(void* const* d_in, const int* in_sizes, int n_in,
                              void* d_out, int out_size, void* d_ws, size_t ws_size,
                              hipStream_t stream) {
  const float* x      = (const float*)d_in[0];
  const int*   ei     = (const int*)d_in[1];
  const float* W_in   = (const float*)d_in[2];
  const float* b_in   = (const float*)d_in[3];
  const float* Ws     = (const float*)d_in[4];
  const float* bs     = (const float*)d_in[5];
  const float* gammas = (const float*)d_in[6];
  const float* betas  = (const float*)d_in[7];
  const float* mean   = (const float*)d_in[8];
  const float* var    = (const float*)d_in[9];
  const float* W_out  = (const float*)d_in[10];
  const float* b_out  = (const float*)d_in[11];
  float* out = (float*)d_out;

  const int N = in_sizes[0] / 128;
  const int E = in_sizes[1] / 2;
  const int* src = ei;
  const int* dst = ei + E;

  char* ws = (char*)d_ws;
  size_t off = 0;
  auto alloc = [&](size_t bytes) {
    void* p = ws + off;
    off = (off + bytes + 255) & ~255ULL;
    return p;
  };
  int*    counts   = (int*)alloc((size_t)N * 4);
  int*    rowstart = (int*)alloc((size_t)N * 4);
  int*    bsum     = (int*)alloc(256 * 4);
  int*    boff     = (int*)alloc(256 * 4);
  float*  dis      = (float*)alloc((size_t)N * 4);
  float*  scale    = (float*)alloc(5 * 128 * 4);
  float*  shift    = (float*)alloc(5 * 128 * 4);
  __bf16* wfrag    = (__bf16*)alloc(360448);  // 5*64KB + 32KB fragment-ordered W
  int*    rank     = (int*)alloc((size_t)E * 4);
  int*    esrc     = (int*)alloc((size_t)E * 4);
  __bf16* tA       = (__bf16*)alloc(((size_t)N + 1) * 128 * 2);  // +1 zero pad row
  __bf16* tB       = (__bf16*)alloc(((size_t)N + 1) * 128 * 2);
  (void)ws_size;

  const int nb = (N + 1023) / 1024;

  hipMemsetAsync(counts, 0, (size_t)N * 4, stream);
  k_count<<<(E + 255) / 256, 256, 0, stream>>>(dst, counts, rank, E);
  k_dis<<<(N + 255) / 256, 256, 0, stream>>>(counts, dis, N);
  k_scan1<<<nb, 256, 0, stream>>>(counts, rowstart, bsum, N);
  k_scan2<<<1, 256, 0, stream>>>(bsum, boff, nb);
  k_fix<<<(N + 255) / 256, 256, 0, stream>>>(rowstart, boff, N);
  k_scatter<<<(E + 255) / 256, 256, 0, stream>>>(src, dst, rowstart, rank, esrc, E);
  k_bnparam<<<(5 * 128 + 255) / 256, 256, 0, stream>>>(gammas, betas, mean, var,
                                                       scale, shift, 5 * 128);
  k_wprep<<<44, 256, 0, stream>>>(W_in, Ws, W_out, wfrag);
  k_zrow<<<1, 64, 0, stream>>>(tA, N);
  k_zrow<<<1, 64, 0, stream>>>(tB, N);

  const int gblocks = (N + 127) / 128;
  const int lblocks = (N + 63) / 64;

  // t0' = dis * (bf16(x) @ W_in)  -> tA
  k_mgemm0<<<gblocks, 256, 0, stream>>>(x, wfrag, dis, tA, N);

  const float* biases[5] = {b_in, bs, bs + 128, bs + 256, bs + 384};
  __bf16* tin = tA;
  __bf16* tout = tB;
  for (int l = 1; l <= 4; ++l) {
    k_layer<8, false><<<lblocks, 256, 0, stream>>>(
        tin, wfrag + (size_t)l * 32768, rowstart, counts, esrc, dis,
        biases[l - 1], scale + (l - 1) * 128, shift + (l - 1) * 128, nullptr,
        nullptr, tout, N);
    __bf16* tmp = tin;
    tin = tout;
    tout = tmp;
  }
  k_layer<4, true><<<lblocks, 256, 0, stream>>>(
      tin, wfrag + 163840, rowstart, counts, esrc, dis, biases[4],
      scale + 4 * 128, shift + 4 * 128, b_out, out, nullptr, N);
}

// Round 11
// 285.466 us; speedup vs baseline: 2.6009x; 1.0278x over previous
//
#include <hip/hip_runtime.h>
#include <cstdint>

#define BN_EPS 1e-5f

typedef __bf16 bf16x8 __attribute__((ext_vector_type(8)));
typedef __bf16 bf16x4 __attribute__((ext_vector_type(4)));
typedef __bf16 bf16x2 __attribute__((ext_vector_type(2)));
typedef float f32x4 __attribute__((ext_vector_type(4)));

// ---------- CSR build ----------

// count in-degree AND record each edge's rank within its dst list
__global__ __launch_bounds__(256) void k_count(const int* __restrict__ dstv,
                                               int* __restrict__ counts,
                                               int* __restrict__ rank, int E) {
  int e = blockIdx.x * 256 + threadIdx.x;
  if (e < E) rank[e] = atomicAdd(counts + dstv[e], 1);
}

// per-block (1024 elems) exclusive scan; block total -> bsum; also dis = rsqrt(deg+1)
__global__ __launch_bounds__(256) void k_scan1(const int* __restrict__ counts,
                                               int* __restrict__ rowstart,
                                               int* __restrict__ bsum,
                                               float* __restrict__ dis, int N) {
  __shared__ int wsum[4];
  const int tid = threadIdx.x, lane = tid & 63, wv = tid >> 6;
  const int base = blockIdx.x * 1024 + tid * 4;
  int c[4];
#pragma unroll
  for (int j = 0; j < 4; ++j) {
    int idx = base + j;
    c[j] = (idx < N) ? counts[idx] : 0;
    if (idx < N) dis[idx] = rsqrtf((float)c[j] + 1.0f);
  }
  int s = c[0] + c[1] + c[2] + c[3];
  int x = s;  // inclusive wave scan
  for (int d = 1; d < 64; d <<= 1) {
    int y = __shfl_up(x, d);
    if (lane >= d) x += y;
  }
  if (lane == 63) wsum[wv] = x;
  __syncthreads();
  int woff = 0;
  for (int w = 0; w < wv; ++w) woff += wsum[w];
  int r = woff + x - s;
#pragma unroll
  for (int j = 0; j < 4; ++j) {
    int idx = base + j;
    if (idx < N) rowstart[idx] = r;
    r += c[j];
  }
  if (tid == 255) bsum[blockIdx.x] = woff + x;
}

__global__ __launch_bounds__(256) void k_scan2(const int* __restrict__ bsum,
                                               int* __restrict__ boff, int nb) {
  __shared__ int sm[256];
  const int tid = threadIdx.x;
  int v = (tid < nb) ? bsum[tid] : 0;
  sm[tid] = v;
  __syncthreads();
  for (int d = 1; d < 256; d <<= 1) {
    int y = (tid >= d) ? sm[tid - d] : 0;
    __syncthreads();
    sm[tid] += y;
    __syncthreads();
  }
  if (tid < nb) boff[tid] = sm[tid] - v;
}

__global__ __launch_bounds__(256) void k_fix(int* __restrict__ rowstart,
                                             const int* __restrict__ boff, int N) {
  int i = blockIdx.x * 256 + threadIdx.x;
  if (i < N) rowstart[i] += boff[i >> 10];
}

// atomic-free placement: esrc[rowstart[dst] + rank] = src
__global__ __launch_bounds__(256) void k_scatter(const int* __restrict__ src,
                                                 const int* __restrict__ dstv,
                                                 const int* __restrict__ rowstart,
                                                 const int* __restrict__ rank,
                                                 int* __restrict__ esrc, int E) {
  int e = blockIdx.x * 256 + threadIdx.x;
  if (e < E) esrc[rowstart[dstv[e]] + rank[e]] = src[e];
}

// ---------- fused prep: wprep (idx<11264) + bnparam (640) + zrow tA/tB ----------
// wprep: fp32 W -> bf16 hi/lo in MFMA fragment order. Per layer, per
// kc_i(4) x plane(2) x ct(CT): 1KB block of 64 lanes x 16B. Lane (lr,kg) holds
// W[k0..k0+8)[ct*16+lr], k0=kc_i*32+kg*8. Layers 0..4: CT=8 @ l*64KB; final:
// CT=4 @ 320KB.
__global__ __launch_bounds__(256) void k_prep(
    const float* __restrict__ W_in, const float* __restrict__ Ws,
    const float* __restrict__ W_out, __bf16* __restrict__ wfrag,
    const float* __restrict__ gamma, const float* __restrict__ beta,
    const float* __restrict__ mean, const float* __restrict__ var,
    float* __restrict__ scale, float* __restrict__ shift,
    __bf16* __restrict__ tA, __bf16* __restrict__ tB, int N) {
  const int idx = blockIdx.x * 256 + threadIdx.x;
  if (idx < 11264) {
    int l, r, CT;
    if (idx < 10240) { l = idx >> 11; r = idx & 2047; CT = 8; }
    else             { l = 5; r = idx - 10240; CT = 4; }
    const int lane = r & 63;
    const int rr = r >> 6;
    const int ct = rr % CT;
    const int kc_i = rr / CT;
    const int lr = lane & 15, kg = lane >> 4;
    const int col = ct * 16 + lr;
    const int k0 = kc_i * 32 + kg * 8;
    const float* Wsrc;
    int ncols;
    if (l == 0)      { Wsrc = W_in; ncols = 128; }
    else if (l <= 4) { Wsrc = Ws + (size_t)(l - 1) * 16384; ncols = 128; }
    else             { Wsrc = W_out; ncols = 64; }
    bf16x8 hi, lo;
#pragma unroll
    for (int j = 0; j < 8; ++j) {
      float v = Wsrc[(size_t)(k0 + j) * ncols + col];
      __bf16 h = (__bf16)v;
      hi[j] = h;
      lo[j] = (__bf16)(v - (float)h);
    }
    const size_t lbase = (l < 5) ? (size_t)l * 65536 : (size_t)327680;
    char* outp = (char*)wfrag + lbase;
    *(bf16x8*)(outp + ((size_t)(kc_i * 2 + 0) * CT + ct) * 1024 + lane * 16) = hi;
    *(bf16x8*)(outp + ((size_t)(kc_i * 2 + 1) * CT + ct) * 1024 + lane * 16) = lo;
  } else if (idx < 11904) {
    const int i = idx - 11264;  // 640 BN channels
    const float s = gamma[i] * rsqrtf(var[i] + BN_EPS);
    scale[i] = s;
    shift[i] = beta[i] - mean[i] * s;
  } else if (idx < 11968) {
    const int lane = idx - 11904;  // zero pad row N of tA
    bf16x2 z; z[0] = (__bf16)0.f; z[1] = (__bf16)0.f;
    *reinterpret_cast<bf16x2*>(tA + (size_t)N * 128 + lane * 2) = z;
  } else if (idx < 12032) {
    const int lane = idx - 11968;  // zero pad row N of tB
    bf16x2 z; z[0] = (__bf16)0.f; z[1] = (__bf16)0.f;
    *reinterpret_cast<bf16x2*>(tB + (size_t)N * 128 + lane * 2) = z;
  }
}

// ---------- MFMA GEMM for layer 0: t' = dis * (bf16(x) @ W_in) ----------
__global__ __launch_bounds__(256, 4) void k_mgemm0(
    const float* __restrict__ in, const __bf16* __restrict__ wfrag,
    const float* __restrict__ dis, __bf16* __restrict__ outh, int N) {
  constexpr int CT = 8;
  __shared__ __align__(16) char Abase[32768];  // [128 rows][128 k] bf16, swizzled

  const int tid = threadIdx.x;
  const int lane = tid & 63;
  const int wv = tid >> 6;
  const int lr = lane & 15;
  const int kg = lane >> 4;
  const int rowBase = blockIdx.x * 128;

  {
    const int kq = tid & 31;  // float4 slot within row
#pragma unroll
    for (int i = 0; i < 16; ++i) {
      const int row = (tid >> 5) + i * 8;
      const int grow = rowBase + row;
      float4 v = make_float4(0.f, 0.f, 0.f, 0.f);
      if (grow < N) v = *(const float4*)(in + (size_t)grow * 128 + kq * 4);
      bf16x4 h;
      h[0] = (__bf16)v.x; h[1] = (__bf16)v.y; h[2] = (__bf16)v.z; h[3] = (__bf16)v.w;
      int byte = row * 256 + kq * 8;
      byte ^= (row & 7) << 4;
      *(bf16x4*)(Abase + byte) = h;
    }
  }
  __syncthreads();

  f32x4 acc[2][CT] = {};
#pragma unroll
  for (int kc_i = 0; kc_i < 4; ++kc_i) {
    bf16x8 afr[2];
#pragma unroll
    for (int rt = 0; rt < 2; ++rt) {
      const int row = wv * 32 + rt * 16 + lr;
      int byte = row * 256 + kc_i * 64 + kg * 16;
      byte ^= (row & 7) << 4;
      afr[rt] = *(const bf16x8*)(Abase + byte);
    }
    const char* wk = (const char*)wfrag + (size_t)kc_i * (2 * CT * 1024) +
                     (size_t)lane * 16;
#pragma unroll
    for (int ct = 0; ct < CT; ++ct) {
      bf16x8 bhi = *(const bf16x8*)(wk + ct * 1024);
      bf16x8 blo = *(const bf16x8*)(wk + (CT + ct) * 1024);
#pragma unroll
      for (int rt = 0; rt < 2; ++rt) {
        acc[rt][ct] = __builtin_amdgcn_mfma_f32_16x16x32_bf16(afr[rt], bhi,
                                                              acc[rt][ct], 0, 0, 0);
        acc[rt][ct] = __builtin_amdgcn_mfma_f32_16x16x32_bf16(afr[rt], blo,
                                                              acc[rt][ct], 0, 0, 0);
      }
    }
  }

#pragma unroll
  for (int rt = 0; rt < 2; ++rt) {
#pragma unroll
    for (int j = 0; j < 4; ++j) {
      const int row = rowBase + wv * 32 + rt * 16 + kg * 4 + j;
      if (row < N) {
        const float dr = dis[row];
#pragma unroll
        for (int ct = 0; ct < CT; ++ct)
          outh[(size_t)row * 128 + ct * 16 + lr] = (__bf16)(acc[rt][ct][j] * dr);
      }
    }
  }
}

// ---------- FUSED layer: [pair-pipelined gather + BN + ReLU -> LDS] -> MFMA ----------
// BM=64, 4 waves; wave wv owns rows wv*16..wv*16+15. Nodes processed in PAIRS:
// issue node i's 8 gathers AND node i+1's 8 gathers (16 in flight), prefetch
// pair i+2's records, then accumulate — doubles outstanding-miss depth vs
// per-node drain. Lanes >= cnt hold zero-row N (padding adds 0). No cross-wave
// LDS sharing -> no __syncthreads(); 16KB LDS, 6 blocks/CU.
template <int CT, bool FINAL>
__global__ __launch_bounds__(256, 6) void k_layer(
    const __bf16* __restrict__ tin, const __bf16* __restrict__ wfrag,
    const int* __restrict__ rowstart, const int* __restrict__ counts,
    const int* __restrict__ esrc, const float* __restrict__ dis,
    const float* __restrict__ bias, const float* __restrict__ scale,
    const float* __restrict__ shift, const float* __restrict__ out_bias,
    float* __restrict__ outf, __bf16* __restrict__ outh, int N) {
  __shared__ __align__(16) char Abase[16384];  // [64 rows][128 k] bf16, swizzled

  const int tid = threadIdx.x;
  const int lane = tid & 63;
  const int wv = tid >> 6;
  const int lr = lane & 15;
  const int kg = lane >> 4;
  const int rowBase = blockIdx.x * 64;

  // ---- phase 1: gather + BN + ReLU for this wave's 16 rows, in pairs ----
  {
    const int nb0 = rowBase + wv * 16;
    // lane-parallel metadata for the 16 nodes (lane<16)
    int mb = 0, mc = 0, mdbits = 0;
    if (lane < 16) {
      const int nd = nb0 + lane;
      if (nd < N) {
        mb = rowstart[nd];
        mc = counts[nd];
        mdbits = __float_as_int(dis[nd]);
      }
    }
    const int f0 = lane * 2;
    const float bx = bias[f0], by = bias[f0 + 1];
    const float scx = scale[f0], scy = scale[f0 + 1];
    const float shx = shift[f0], shy = shift[f0 + 1];

    // preload records for nodes 0,1
    int c0 = __builtin_amdgcn_readlane(mc, 0);
    int c1 = __builtin_amdgcn_readlane(mc, 1);
    int rec0 = (lane < c0) ? esrc[__builtin_amdgcn_readlane(mb, 0) + lane] : N;
    int rec1 = (lane < c1) ? esrc[__builtin_amdgcn_readlane(mb, 1) + lane] : N;

    for (int i = 0; i < 16; i += 2) {
      const int node0 = nb0 + i, node1 = nb0 + i + 1;
      const int sr0 = (node0 < N) ? node0 : N;
      const int sr1 = (node1 < N) ? node1 : N;
      const bf16x2 sv0 = *(const bf16x2*)(tin + (size_t)sr0 * 128 + f0);
      const bf16x2 sv1 = *(const bf16x2*)(tin + (size_t)sr1 * 128 + f0);

      // burst: 8 gathers for node0 AND 8 for node1 (16 outstanding)
      bf16x2 g0[8], g1[8];
#pragma unroll
      for (int u = 0; u < 8; ++u) {
        const int s = __builtin_amdgcn_readlane(rec0, u);
        g0[u] = *(const bf16x2*)(tin + (size_t)s * 128 + f0);
      }
#pragma unroll
      for (int u = 0; u < 8; ++u) {
        const int s = __builtin_amdgcn_readlane(rec1, u);
        g1[u] = *(const bf16x2*)(tin + (size_t)s * 128 + f0);
      }

      // prefetch next pair's records (flies during accumulation)
      int recn0 = N, recn1 = N, cn0 = 0, cn1 = 0;
      if (i < 14) {
        cn0 = __builtin_amdgcn_readlane(mc, i + 2);
        cn1 = __builtin_amdgcn_readlane(mc, i + 3);
        const int bn0 = __builtin_amdgcn_readlane(mb, i + 2);
        const int bn1 = __builtin_amdgcn_readlane(mb, i + 3);
        if (lane < cn0) recn0 = esrc[bn0 + lane];
        if (lane < cn1) recn1 = esrc[bn1 + lane];
      }

      // ---- accumulate node0 ----
      float ax = (float)sv0[0], ay = (float)sv0[1];
#pragma unroll
      for (int u = 0; u < 8; ++u) {
        ax += (float)g0[u][0];
        ay += (float)g0[u][1];
      }
      if (__builtin_expect(c0 > 8, 0)) {
        const int m = c0 < 64 ? c0 : 64;
        for (int rb = 8; rb < m; rb += 8) {
#pragma unroll
          for (int u = 0; u < 8; ++u) {
            const int s = __builtin_amdgcn_readlane(rec0, rb + u);
            const bf16x2 v = *(const bf16x2*)(tin + (size_t)s * 128 + f0);
            ax += (float)v[0];
            ay += (float)v[1];
          }
        }
        if (c0 > 64) {
          const int bi = __builtin_amdgcn_readlane(mb, i);
          for (int e = 64; e < c0; ++e) {
            const int s0 = esrc[bi + e];
            const bf16x2 v0 = *(const bf16x2*)(tin + (size_t)s0 * 128 + f0);
            ax += (float)v0[0];
            ay += (float)v0[1];
          }
        }
      }
      {
        const float dn = __int_as_float(__builtin_amdgcn_readlane(mdbits, i));
        float tx = fmaf(ax, dn, bx), ty = fmaf(ay, dn, by);
        tx = fmaxf(fmaf(tx, scx, shx), 0.f);
        ty = fmaxf(fmaf(ty, scy, shy), 0.f);
        bf16x2 o;
        o[0] = (__bf16)tx;
        o[1] = (__bf16)ty;
        const int row = wv * 16 + i;
        int byte = row * 256 + lane * 4;
        byte ^= (row & 7) << 4;
        *(bf16x2*)(Abase + byte) = o;
      }

      // ---- accumulate node1 ----
      ax = (float)sv1[0];
      ay = (float)sv1[1];
#pragma unroll
      for (int u = 0; u < 8; ++u) {
        ax += (float)g1[u][0];
        ay += (float)g1[u][1];
      }
      if (__builtin_expect(c1 > 8, 0)) {
        const int m = c1 < 64 ? c1 : 64;
        for (int rb = 8; rb < m; rb += 8) {
#pragma unroll
          for (int u = 0; u < 8; ++u) {
            const int s = __builtin_amdgcn_readlane(rec1, rb + u);
            const bf16x2 v = *(const bf16x2*)(tin + (size_t)s * 128 + f0);
            ax += (float)v[0];
            ay += (float)v[1];
          }
        }
        if (c1 > 64) {
          const int bi = __builtin_amdgcn_readlane(mb, i + 1);
          for (int e = 64; e < c1; ++e) {
            const int s0 = esrc[bi + e];
            const bf16x2 v0 = *(const bf16x2*)(tin + (size_t)s0 * 128 + f0);
            ax += (float)v0[0];
            ay += (float)v0[1];
          }
        }
      }
      {
        const float dn = __int_as_float(__builtin_amdgcn_readlane(mdbits, i + 1));
        float tx = fmaf(ax, dn, bx), ty = fmaf(ay, dn, by);
        tx = fmaxf(fmaf(tx, scx, shx), 0.f);
        ty = fmaxf(fmaf(ty, scy, shy), 0.f);
        bf16x2 o;
        o[0] = (__bf16)tx;
        o[1] = (__bf16)ty;
        const int row = wv * 16 + i + 1;
        int byte = row * 256 + lane * 4;
        byte ^= (row & 7) << 4;
        *(bf16x2*)(Abase + byte) = o;
      }

      rec0 = recn0;
      rec1 = recn1;
      c0 = cn0;
      c1 = cn1;
    }
  }
  // same-wave LDS RAW only (wave reads just its own 16 rows) — no barrier
  __threadfence_block();

  // ---- phase 2: MFMA (A from LDS, W fragments direct from L2) ----
  f32x4 acc[CT] = {};
#pragma unroll
  for (int kc_i = 0; kc_i < 4; ++kc_i) {
    const int row = wv * 16 + lr;
    int byte = row * 256 + kc_i * 64 + kg * 16;
    byte ^= (row & 7) << 4;
    const bf16x8 afr = *(const bf16x8*)(Abase + byte);
    const char* wk = (const char*)wfrag + (size_t)kc_i * (2 * CT * 1024) +
                     (size_t)lane * 16;
#pragma unroll
    for (int ct = 0; ct < CT; ++ct) {
      bf16x8 bhi = *(const bf16x8*)(wk + ct * 1024);
      bf16x8 blo = *(const bf16x8*)(wk + (CT + ct) * 1024);
      acc[ct] = __builtin_amdgcn_mfma_f32_16x16x32_bf16(afr, bhi, acc[ct], 0, 0, 0);
      acc[ct] = __builtin_amdgcn_mfma_f32_16x16x32_bf16(afr, blo, acc[ct], 0, 0, 0);
    }
  }

  // ---- epilogue: C/D layout col=lane&15, row=(lane>>4)*4+j ----
  float ob[CT];
  if constexpr (FINAL) {
#pragma unroll
    for (int ct = 0; ct < CT; ++ct) ob[ct] = out_bias[ct * 16 + lr];
  }
#pragma unroll
  for (int j = 0; j < 4; ++j) {
    const int row = rowBase + wv * 16 + kg * 4 + j;
    if (row < N) {
      if constexpr (FINAL) {
#pragma unroll
        for (int ct = 0; ct < CT; ++ct)
          outf[(size_t)row * (CT * 16) + ct * 16 + lr] = acc[ct][j] + ob[ct];
      } else {
        const float dr = dis[row];
#pragma unroll
        for (int ct = 0; ct < CT; ++ct)
          outh[(size_t)row * 128 + ct * 16 + lr] = (__bf16)(acc[ct][j] * dr);
      }
    }
  }
}

// ---------- launch ----------
extern "C" void kernel_launch(void* const* d_in, const int* in_sizes, int n_in,
                              void* d_out, int out_size, void* d_ws, size_t ws_size,
                              hipStream_t stream) {
  const float* x      = (const float*)d_in[0];
  const int*   ei     = (const int*)d_in[1];
  const float* W_in   = (const float*)d_in[2];
  const float* b_in   = (const float*)d_in[3];
  const float* Ws     = (const float*)d_in[4];
  const float* bs     = (const float*)d_in[5];
  const float* gammas = (const float*)d_in[6];
  const float* betas  = (const float*)d_in[7];
  const float* mean   = (const float*)d_in[8];
  const float* var    = (const float*)d_in[9];
  const float* W_out  = (const float*)d_in[10];
  const float* b_out  = (const float*)d_in[11];
  float* out = (float*)d_out;

  const int N = in_sizes[0] / 128;
  const int E = in_sizes[1] / 2;
  const int* src = ei;
  const int* dst = ei + E;

  char* ws = (char*)d_ws;
  size_t off = 0;
  auto alloc = [&](size_t bytes) {
    void* p = ws + off;
    off = (off + bytes + 255) & ~255ULL;
    return p;
  };
  int*    counts   = (int*)alloc((size_t)N * 4);
  int*    rowstart = (int*)alloc((size_t)N * 4);
  int*    bsum     = (int*)alloc(256 * 4);
  int*    boff     = (int*)alloc(256 * 4);
  float*  dis      = (float*)alloc((size_t)N * 4);
  float*  scale    = (float*)alloc(5 * 128 * 4);
  float*  shift    = (float*)alloc(5 * 128 * 4);
  __bf16* wfrag    = (__bf16*)alloc(360448);  // 5*64KB + 32KB fragment-ordered W
  int*    rank     = (int*)alloc((size_t)E * 4);
  int*    esrc     = (int*)alloc((size_t)E * 4);
  __bf16* tA       = (__bf16*)alloc(((size_t)N + 1) * 128 * 2);  // +1 zero pad row
  __bf16* tB       = (__bf16*)alloc(((size_t)N + 1) * 128 * 2);
  (void)ws_size;

  const int nb = (N + 1023) / 1024;

  hipMemsetAsync(counts, 0, (size_t)N * 4, stream);
  k_count<<<(E + 255) / 256, 256, 0, stream>>>(dst, counts, rank, E);
  k_scan1<<<nb, 256, 0, stream>>>(counts, rowstart, bsum, dis, N);
  k_scan2<<<1, 256, 0, stream>>>(bsum, boff, nb);
  k_fix<<<(N + 255) / 256, 256, 0, stream>>>(rowstart, boff, N);
  k_scatter<<<(E + 255) / 256, 256, 0, stream>>>(src, dst, rowstart, rank, esrc, E);
  k_prep<<<47, 256, 0, stream>>>(W_in, Ws, W_out, wfrag, gammas, betas, mean, var,
                                 scale, shift, tA, tB, N);

  const int gblocks = (N + 127) / 128;
  const int lblocks = (N + 63) / 64;

  // t0' = dis * (bf16(x) @ W_in)  -> tA
  k_mgemm0<<<gblocks, 256, 0, stream>>>(x, wfrag, dis, tA, N);

  const float* biases[5] = {b_in, bs, bs + 128, bs + 256, bs + 384};
  __bf16* tin = tA;
  __bf16* tout = tB;
  for (int l = 1; l <= 4; ++l) {
    k_layer<8, false><<<lblocks, 256, 0, stream>>>(
        tin, wfrag + (size_t)l * 32768, rowstart, counts, esrc, dis,
        biases[l - 1], scale + (l - 1) * 128, shift + (l - 1) * 128, nullptr,
        nullptr, tout, N);
    __bf16* tmp = tin;
    tin = tout;
    tout = tmp;
  }
  k_layer<4, true><<<lblocks, 256, 0, stream>>>(
      tin, wfrag + 163840, rowstart, counts, esrc, dis, biases[4],
      scale + 4 * 128, shift + 4 * 128, b_out, out, nullptr, N);
}